// Round 4
// baseline (249.967 us; speedup 1.0000x reference)
//
#include <hip/hip_runtime.h>
#include <math.h>

// DNC single step, MI355X. All f32. B=16,N=2048,M=64,R=4,H=512.
constexpr int BB = 16, NN = 2048, MM = 64, RR = 4, HH = 512;
constexpr int CIN = 320, COUT = 535;
constexpr int CHUNKS = 64, ROWS = 32; // link kernel row-chunking (512 thr/block)

typedef float f32x4 __attribute__((ext_vector_type(4)));

// ---- output layout (floats): output, memory_new, link_new, p_new, usage, read_w
constexpr size_t O_OUT   = 0;
constexpr size_t O_MEM   = O_OUT + (size_t)BB * 64;
constexpr size_t O_LINK  = O_MEM + (size_t)BB * NN * MM;
constexpr size_t O_PNEW  = O_LINK + (size_t)BB * NN * NN;
constexpr size_t O_USAGE = O_PNEW + (size_t)BB * NN;
constexpr size_t O_READW = O_USAGE + (size_t)BB * NN;

// ---- workspace layout (floats)
constexpr size_t WS_H     = 0;                                   // B*512
constexpr size_t WS_OUTR  = WS_H + (size_t)BB * HH;              // B*535 (raw, for modes)
constexpr size_t WS_TASK  = WS_OUTR + (size_t)BB * COUT;         // B*64
constexpr size_t WS_RKEYS = WS_TASK + (size_t)BB * 64;           // B*256
constexpr size_t WS_RBETA = WS_RKEYS + (size_t)BB * 256;         // B*4
constexpr size_t WS_FGATE = WS_RBETA + (size_t)BB * 4;           // B*4
constexpr size_t WS_WKEY  = WS_FGATE + (size_t)BB * 4;           // B*64
constexpr size_t WS_WBETA = WS_WKEY + (size_t)BB * 64;           // B
constexpr size_t WS_ERASE = WS_WBETA + (size_t)BB;               // B*64
constexpr size_t WS_WVEC  = WS_ERASE + (size_t)BB * 64;          // B*64
constexpr size_t WS_AGATE = WS_WVEC + (size_t)BB * 64;           // B
constexpr size_t WS_WGATE = WS_AGATE + (size_t)BB;               // B
constexpr size_t WS_CONT  = WS_WGATE + (size_t)BB;               // B*5*N
constexpr size_t WS_WW    = WS_CONT + (size_t)BB * 5 * NN;       // B*N
constexpr size_t WS_FWD   = WS_WW + (size_t)BB * NN;             // B*4*N
constexpr size_t WS_BPART = WS_FWD + (size_t)BB * 4 * NN;        // B*CHUNKS*4*N
constexpr size_t WS_RPART = WS_BPART + (size_t)BB * CHUNKS * 4 * NN; // B*8*256
constexpr size_t WS_TOTAL = WS_RPART + (size_t)BB * 8 * 256;

__device__ __forceinline__ float sigf(float x) { return 1.0f / (1.0f + expf(-x)); }
__device__ __forceinline__ float oneplusf(float x) {
  return 1.0f + fmaxf(x, 0.0f) + log1pf(expf(-fabsf(x)));
}

// ---- K1: LSTM gates + cell fused. One block per hidden index j.
__global__ void k_gates_lstm(const float* __restrict__ task, const float* __restrict__ prev_reads,
                             const float* __restrict__ h_prev, const float* __restrict__ c_prev,
                             const float* __restrict__ W_ih, const float* __restrict__ W_hh,
                             const float* __restrict__ b_lstm, float* __restrict__ ws) {
  int tid = threadIdx.x, lane = tid & 63, wave = tid >> 6;
  int j = blockIdx.x;            // 0..511
  int row = wave * HH + j;       // gate row in [0,2048)
  __shared__ float gv[4][16];
  float acc[16];
#pragma unroll
  for (int b = 0; b < 16; b++) acc[b] = 0.f;
#pragma unroll
  for (int s = 0; s < 5; s++) {
    int k = s * 64 + lane;
    float wv = W_ih[(size_t)row * CIN + k];
    if (s == 0) {
#pragma unroll
      for (int b = 0; b < 16; b++) acc[b] += wv * task[b * 64 + k];
    } else {
#pragma unroll
      for (int b = 0; b < 16; b++) acc[b] += wv * prev_reads[b * 256 + (k - 64)];
    }
  }
#pragma unroll
  for (int s = 0; s < 8; s++) {
    int k = s * 64 + lane;
    float wv = W_hh[(size_t)row * HH + k];
#pragma unroll
    for (int b = 0; b < 16; b++) acc[b] += wv * h_prev[b * HH + k];
  }
#pragma unroll
  for (int b = 0; b < 16; b++) {
#pragma unroll
    for (int off = 32; off >= 1; off >>= 1) acc[b] += __shfl_xor(acc[b], off);
  }
  float val = 0.f;
#pragma unroll
  for (int b = 0; b < 16; b++) if (lane == b) val = acc[b];
  if (lane < 16) gv[wave][lane] = val + b_lstm[row];
  __syncthreads();
  if (tid < 16) {
    int b = tid;
    float gi = gv[0][b], gf = gv[1][b], gg = gv[2][b], go = gv[3][b];
    float c = sigf(gf) * c_prev[b * HH + j] + sigf(gi) * tanhf(gg);
    ws[WS_H + (size_t)b * HH + j] = sigf(go) * tanhf(c);
  }
}

// ---- K2: out_raw = h @ W_out^T + b_out, fused parse (one wave per row j<535)
__global__ void k_outproj_parse(const float* __restrict__ W_out, const float* __restrict__ b_out,
                                float* __restrict__ ws) {
  int tid = threadIdx.x, lane = tid & 63, wave = tid >> 6;
  int j = blockIdx.x * 4 + wave;
  if (j >= COUT) return;
  float acc[16];
#pragma unroll
  for (int b = 0; b < 16; b++) acc[b] = 0.f;
#pragma unroll
  for (int s = 0; s < 8; s++) {
    int k = s * 64 + lane;
    float wv = W_out[j * HH + k];
#pragma unroll
    for (int b = 0; b < 16; b++) acc[b] += wv * ws[WS_H + (size_t)b * HH + k];
  }
#pragma unroll
  for (int b = 0; b < 16; b++) {
#pragma unroll
    for (int off = 32; off >= 1; off >>= 1) acc[b] += __shfl_xor(acc[b], off);
  }
  float bias = b_out[j];
  float val = 0.f;
#pragma unroll
  for (int b = 0; b < 16; b++) if (lane == b) val = acc[b];
  if (lane < 16) {
    int b = lane;
    float v = val + bias;
    ws[WS_OUTR + (size_t)b * COUT + j] = v; // raw kept for read-mode softmax
    if (j < 64)       ws[WS_TASK + b * 64 + j] = sigf(v);
    else if (j < 320) ws[WS_RKEYS + b * 256 + (j - 64)] = sigf(v);
    else if (j < 324) ws[WS_RBETA + b * 4 + (j - 320)] = oneplusf(v);
    else if (j < 328) ws[WS_FGATE + b * 4 + (j - 324)] = sigf(v);
    else if (j < 392) ws[WS_WKEY + b * 64 + (j - 328)] = sigf(v);
    else if (j == 392) ws[WS_WBETA + b] = oneplusf(v);
    else if (j < 457) ws[WS_ERASE + b * 64 + (j - 393)] = sigf(v);
    else if (j < 521) ws[WS_WVEC + b * 64 + (j - 457)] = sigf(v);
    else if (j == 521) ws[WS_AGATE + b] = sigf(v);
    else if (j == 522) ws[WS_WGATE + b] = sigf(v);
  }
}

// ---- K3: content scores + softmax, one block per (b,key) (fused)
__global__ void __launch_bounds__(1024) k_content(const float* __restrict__ memory,
                                                  float* __restrict__ ws) {
  int bk = blockIdx.x; // b*5+k
  int b = bk / 5, k = bk % 5;
  int t = threadIdx.x, lane = t & 63, wave = t >> 6;
  __shared__ __align__(16) float kb[64];
  __shared__ float sc[NN];
  __shared__ float red[16];
  __shared__ float skn, sbeta;
  if (t < 64) kb[t] = (k < 4) ? ws[WS_RKEYS + b * 256 + k * 64 + t] : ws[WS_WKEY + b * 64 + t];
  if (t == 64) sbeta = (k < 4) ? ws[WS_RBETA + b * 4 + k] : ws[WS_WBETA + b];
  __syncthreads();
  if (wave == 0) {
    float kv = kb[lane];
    float ss = kv * kv;
#pragma unroll
    for (int off = 32; off >= 1; off >>= 1) ss += __shfl_xor(ss, off);
    if (lane == 0) skn = sqrtf(ss);
  }
  __syncthreads();
  float kn = skn, beta = sbeta;
  int r = lane >> 4, c = lane & 15;
  float4 key4 = *reinterpret_cast<const float4*>(&kb[c * 4]);
  for (int i = 0; i < 32; i++) {
    int n = wave * 128 + i * 4 + r;
    float4 v = *reinterpret_cast<const float4*>(&memory[((size_t)b * NN + n) * MM + c * 4]);
    float d = v.x * key4.x + v.y * key4.y + v.z * key4.z + v.w * key4.w;
    float s2 = v.x * v.x + v.y * v.y + v.z * v.z + v.w * v.w;
#pragma unroll
    for (int off = 1; off <= 8; off <<= 1) {
      d += __shfl_xor(d, off);
      s2 += __shfl_xor(s2, off);
    }
    if (c == 0) sc[n] = beta * d / (kn * sqrtf(s2) + 1e-8f);
  }
  __syncthreads();
  float v0 = sc[t], v1 = sc[t + 1024];
  float mx = fmaxf(v0, v1);
#pragma unroll
  for (int off = 32; off >= 1; off >>= 1) mx = fmaxf(mx, __shfl_xor(mx, off));
  if (lane == 0) red[wave] = mx;
  __syncthreads();
  mx = red[0];
  for (int w2 = 1; w2 < 16; w2++) mx = fmaxf(mx, red[w2]);
  float e0 = expf(v0 - mx), e1 = expf(v1 - mx);
  float s = e0 + e1;
#pragma unroll
  for (int off = 32; off >= 1; off >>= 1) s += __shfl_xor(s, off);
  __syncthreads();
  if (lane == 0) red[wave] = s;
  __syncthreads();
  s = 0.f;
  for (int w2 = 0; w2 < 16; w2++) s += red[w2];
  float inv = 1.f / s;
  float* dst = ws + WS_CONT + (size_t)bk * NN;
  dst[t] = e0 * inv;
  dst[t + 1024] = e1 * inv;
}

// ---- K4: usage + allocation (bitonic sort) + write weights + p_new, one block per b
__global__ void __launch_bounds__(1024) k_write_path(
    const float* __restrict__ prw, const float* __restrict__ pu,
    const float* __restrict__ pww, const float* __restrict__ prec,
    float* __restrict__ ws, float* __restrict__ out) {
  int b = blockIdx.x, t = threadIdx.x, lane = t & 63, wave = t >> 6;
  __shared__ float sv[NN];
  __shared__ int si[NN];
  __shared__ float al[NN];
  __shared__ float wred[16];
  float fg[4];
#pragma unroll
  for (int r = 0; r < 4; r++) fg[r] = ws[WS_FGATE + b * 4 + r];
#pragma unroll
  for (int e = 0; e < 2; e++) {
    int n = t + e * 1024;
    float psi = 1.f;
#pragma unroll
    for (int r = 0; r < 4; r++) psi *= (1.f - fg[r] * prw[((size_t)b * 4 + r) * NN + n]);
    float a = pu[(size_t)b * NN + n], w = pww[(size_t)b * NN + n];
    float u = (a + w - a * w) * psi;
    out[O_USAGE + (size_t)b * NN + n] = u;
    sv[n] = u;
    si[n] = n;
  }
  __syncthreads();
  for (int k = 2; k <= NN; k <<= 1) {
    for (int j = k >> 1; j > 0; j >>= 1) {
#pragma unroll
      for (int e = 0; e < 2; e++) {
        int idx = t + e * 1024;
        int l = idx ^ j;
        if (l > idx) {
          bool up = ((idx & k) == 0);
          float va = sv[idx], vb = sv[l];
          int ia = si[idx], ib = si[l];
          bool lessBA = (vb < va) || (vb == va && ib < ia);
          if (up ? lessBA : !lessBA) { sv[idx] = vb; sv[l] = va; si[idx] = ib; si[l] = ia; }
        }
      }
      __syncthreads();
    }
  }
  float u0 = sv[2 * t], u1 = sv[2 * t + 1];
  int i0 = si[2 * t], i1 = si[2 * t + 1];
  float lp = u0 * u1;
  float x = lp;
#pragma unroll
  for (int off = 1; off < 64; off <<= 1) {
    float y = __shfl_up(x, off);
    if (lane >= off) x *= y;
  }
  if (lane == 63) wred[wave] = x;
  float ex = __shfl_up(x, 1);
  if (lane == 0) ex = 1.f;
  __syncthreads();
  float base = 1.f;
  for (int w2 = 0; w2 < wave; w2++) base *= wred[w2];
  float E = base * ex;
  al[i0] = (1.f - u0) * E;
  E *= u0;
  al[i1] = (1.f - u1) * E;
  __syncthreads();
  float ag = ws[WS_AGATE + b], wg = ws[WS_WGATE + b];
  float wwv[2], ssum = 0.f;
#pragma unroll
  for (int e = 0; e < 2; e++) {
    int n = t + e * 1024;
    float cw = ws[WS_CONT + ((size_t)b * 5 + 4) * NN + n];
    wwv[e] = wg * (ag * al[n] + (1.f - ag) * cw);
    ws[WS_WW + (size_t)b * NN + n] = wwv[e];
    ssum += wwv[e];
  }
#pragma unroll
  for (int off = 32; off >= 1; off >>= 1) ssum += __shfl_xor(ssum, off);
  __syncthreads();
  if (lane == 0) wred[wave] = ssum;
  __syncthreads();
  float tot = 0.f;
  for (int w2 = 0; w2 < 16; w2++) tot += wred[w2];
  float om = 1.f - tot;
#pragma unroll
  for (int e = 0; e < 2; e++) {
    int n = t + e * 1024;
    out[O_PNEW + (size_t)b * NN + n] = om * prec[(size_t)b * NN + n] + wwv[e];
  }
}

// ---- K5: fused streaming pass over L: fwd_w, bwd partials, link_new, memory_new.
// 512 threads (8 waves); 4-row software-pipelined prefetch ring for MLP.
__global__ void __launch_bounds__(512) k_link(const float* __restrict__ L,
                                              const float* __restrict__ wprev,
                                              const float* __restrict__ mem,
                                              float* __restrict__ ws, float* __restrict__ out) {
  int b = blockIdx.y, chunk = blockIdx.x;
  int i0 = chunk * ROWS;
  int tid = threadIdx.x, lane = tid & 63, wave = tid >> 6; // 8 waves
  __shared__ float wwrow[ROWS];
  __shared__ float wprow[4][ROWS];
  __shared__ float fpart[8][4][ROWS];
  if (tid < ROWS) wwrow[tid] = ws[WS_WW + (size_t)b * NN + i0 + tid];
  if (tid >= 64 && tid < 64 + 4 * ROWS) {
    int r = (tid - 64) >> 5, ii = (tid - 64) & 31;
    wprow[r][ii] = wprev[((size_t)b * 4 + r) * NN + i0 + ii];
  }
  int j = tid * 4; // fixed 4 columns per thread
  f32x4 wp[4], pn, wwj;
#pragma unroll
  for (int r = 0; r < 4; r++)
    wp[r] = *reinterpret_cast<const f32x4*>(&wprev[((size_t)b * 4 + r) * NN + j]);
  pn = *reinterpret_cast<const f32x4*>(&out[O_PNEW + (size_t)b * NN + j]);
  wwj = *reinterpret_cast<const f32x4*>(&ws[WS_WW + (size_t)b * NN + j]);
  const float* Lb = L + (size_t)b * NN * NN;
  float* linkb = out + O_LINK + (size_t)b * NN * NN;
  // start the prefetch ring BEFORE the barrier/memnew so loads overlap them
  constexpr int PF = 4;
  f32x4 vbuf[PF];
#pragma unroll
  for (int p = 0; p < PF; p++)
    vbuf[p] = __builtin_nontemporal_load(
        reinterpret_cast<const f32x4*>(Lb + (size_t)(i0 + p) * NN) + tid);
  __syncthreads();
  // fused memory_new for rows i0..i0+ROWS-1 (ROWS*64 = 2048 elems)
#pragma unroll
  for (int e = 0; e < 4; e++) {
    int idx = e * 512 + tid;
    int ii = idx >> 6, m = idx & 63;
    size_t g = ((size_t)b * NN + i0 + ii) * MM + m;
    float wwv = wwrow[ii];
    float mv = mem[g] * (1.f - wwv * ws[WS_ERASE + b * 64 + m]) + wwv * ws[WS_WVEC + b * 64 + m];
    __builtin_nontemporal_store(mv, &out[O_MEM + g]);
  }
  f32x4 bacc[4];
#pragma unroll
  for (int r = 0; r < 4; r++) bacc[r] = (f32x4)(0.f);
#pragma unroll
  for (int ii = 0; ii < ROWS; ii++) {
    f32x4 v = vbuf[ii & (PF - 1)];
    if (ii + PF < ROWS)
      vbuf[ii & (PF - 1)] = __builtin_nontemporal_load(
          reinterpret_cast<const f32x4*>(Lb + (size_t)(i0 + ii + PF) * NN) + tid);
    int i = i0 + ii;
    // fwd partial dots, reduce across 64 lanes
    float f0 = v[0] * wp[0][0] + v[1] * wp[0][1] + v[2] * wp[0][2] + v[3] * wp[0][3];
    float f1 = v[0] * wp[1][0] + v[1] * wp[1][1] + v[2] * wp[1][2] + v[3] * wp[1][3];
    float f2 = v[0] * wp[2][0] + v[1] * wp[2][1] + v[2] * wp[2][2] + v[3] * wp[2][3];
    float f3 = v[0] * wp[3][0] + v[1] * wp[3][1] + v[2] * wp[3][2] + v[3] * wp[3][3];
#pragma unroll
    for (int off = 32; off >= 1; off >>= 1) {
      f0 += __shfl_xor(f0, off);
      f1 += __shfl_xor(f1, off);
      f2 += __shfl_xor(f2, off);
      f3 += __shfl_xor(f3, off);
    }
    if (lane == 0) {
      fpart[wave][0][ii] = f0; fpart[wave][1][ii] = f1;
      fpart[wave][2][ii] = f2; fpart[wave][3][ii] = f3;
    }
    // bwd: column accumulation
#pragma unroll
    for (int r = 0; r < 4; r++) {
      float w = wprow[r][ii];
      bacc[r][0] += w * v[0]; bacc[r][1] += w * v[1];
      bacc[r][2] += w * v[2]; bacc[r][3] += w * v[3];
    }
    // link update + diagonal zero
    float wwi = wwrow[ii];
    f32x4 o;
    o[0] = (1.f - wwi - wwj[0]) * v[0] + wwi * pn[0];
    o[1] = (1.f - wwi - wwj[1]) * v[1] + wwi * pn[1];
    o[2] = (1.f - wwi - wwj[2]) * v[2] + wwi * pn[2];
    o[3] = (1.f - wwi - wwj[3]) * v[3] + wwi * pn[3];
    if (i == j)     o[0] = 0.f;
    if (i == j + 1) o[1] = 0.f;
    if (i == j + 2) o[2] = 0.f;
    if (i == j + 3) o[3] = 0.f;
    __builtin_nontemporal_store(o, reinterpret_cast<f32x4*>(linkb + (size_t)i * NN) + tid);
  }
  __syncthreads();
  if (tid < 4 * ROWS) {
    int r = tid >> 5, ii = tid & 31;
    float s = 0.f;
#pragma unroll
    for (int w2 = 0; w2 < 8; w2++) s += fpart[w2][r][ii];
    ws[WS_FWD + ((size_t)b * 4 + r) * NN + i0 + ii] = s;
  }
#pragma unroll
  for (int r = 0; r < 4; r++)
    *reinterpret_cast<f32x4*>(
        &ws[WS_BPART + (((size_t)b * CHUNKS + chunk) * 4 + r) * NN + j]) = bacc[r];
}

// ---- K6: bwd chunk-reduce + read modes + read_w + read partial dots (fused)
__global__ void __launch_bounds__(256) k_readrw(const float* __restrict__ memory,
                                                float* __restrict__ ws, float* __restrict__ out) {
  int b = blockIdx.x >> 3, chunk = blockIdx.x & 7;
  int n0 = chunk * 256;
  int t = threadIdx.x, lane = t & 63, wave = t >> 6;
  __shared__ float fm[4][3];
  __shared__ float rwl[4][256];
  __shared__ float part[4][4][64];
  if (t < 4) {
    const float* o = ws + WS_OUTR + (size_t)b * COUT + 523 + t * 3;
    float a = o[0], bb = o[1], cc = o[2];
    float m = fmaxf(a, fmaxf(bb, cc));
    float ea = expf(a - m), eb = expf(bb - m), ec = expf(cc - m);
    float iv = 1.f / (ea + eb + ec);
    fm[t][0] = ea * iv; fm[t][1] = eb * iv; fm[t][2] = ec * iv;
  }
  __syncthreads();
#pragma unroll
  for (int r = 0; r < 4; r++) {
    int n = n0 + t;
    float bwd = 0.f;
    for (int c2 = 0; c2 < CHUNKS; c2++)
      bwd += ws[WS_BPART + (((size_t)b * CHUNKS + c2) * 4 + r) * NN + n];
    float fwd = ws[WS_FWD + ((size_t)b * 4 + r) * NN + n];
    float cont = ws[WS_CONT + ((size_t)b * 5 + r) * NN + n];
    float rw = fm[r][0] * bwd + fm[r][1] * cont + fm[r][2] * fwd;
    out[O_READW + ((size_t)b * 4 + r) * NN + n] = rw;
    rwl[r][t] = rw;
  }
  __syncthreads();
  float acc[4] = {0.f, 0.f, 0.f, 0.f};
  for (int ii = 0; ii < 64; ii++) {
    int nl = wave * 64 + ii;
    float mv = memory[((size_t)b * NN + n0 + nl) * MM + lane];
#pragma unroll
    for (int r = 0; r < 4; r++) acc[r] += rwl[r][nl] * mv;
  }
#pragma unroll
  for (int r = 0; r < 4; r++) part[wave][r][lane] = acc[r];
  __syncthreads();
  { int r = t >> 6, m = t & 63;
    float s = part[0][r][m] + part[1][r][m] + part[2][r][m] + part[3][r][m];
    ws[WS_RPART + ((size_t)(b * 8 + chunk)) * 256 + t] = s; }
}

// ---- K7: reduce read partials + read projection + final output
__global__ void k_final(const float* __restrict__ W_read, const float* __restrict__ b_read,
                        const float* __restrict__ ws, float* __restrict__ out) {
  int b = blockIdx.x, t = threadIdx.x, lane = t & 63, wave = t >> 6;
  __shared__ float rds[256];
  float s = 0.f;
  for (int c = 0; c < 8; c++) s += ws[WS_RPART + ((size_t)(b * 8 + c)) * 256 + t];
  rds[t] = s;
  __syncthreads();
  for (int oi = 0; oi < 16; oi++) {
    int o = wave * 16 + oi;
    float acc = 0.f;
#pragma unroll
    for (int s2 = 0; s2 < 4; s2++) {
      int kk = s2 * 64 + lane;
      acc += W_read[o * 256 + kk] * rds[kk];
    }
#pragma unroll
    for (int off = 32; off >= 1; off >>= 1) acc += __shfl_xor(acc, off);
    if (lane == 0) {
      float ro = sigf(acc + b_read[o]);
      out[O_OUT + b * 64 + o] = sigf(ro + ws[WS_TASK + b * 64 + o]);
    }
  }
}

extern "C" void kernel_launch(void* const* d_in, const int* in_sizes, int n_in,
                              void* d_out, int out_size, void* d_ws, size_t ws_size,
                              hipStream_t stream) {
  (void)in_sizes; (void)n_in; (void)out_size; (void)ws_size;
  const float* task   = (const float*)d_in[0];
  const float* memory = (const float*)d_in[1];
  const float* links  = (const float*)d_in[2];
  const float* preads = (const float*)d_in[3];
  const float* prw    = (const float*)d_in[4];
  const float* pusage = (const float*)d_in[5];
  const float* pww    = (const float*)d_in[6];
  const float* prec   = (const float*)d_in[7];
  const float* h_prev = (const float*)d_in[8];
  const float* c_prev = (const float*)d_in[9];
  const float* W_ih   = (const float*)d_in[10];
  const float* W_hh   = (const float*)d_in[11];
  const float* b_lstm = (const float*)d_in[12];
  const float* W_out  = (const float*)d_in[13];
  const float* b_out  = (const float*)d_in[14];
  const float* W_read = (const float*)d_in[15];
  const float* b_read = (const float*)d_in[16];
  float* out = (float*)d_out;
  float* ws  = (float*)d_ws;

  k_gates_lstm<<<512, 256, 0, stream>>>(task, preads, h_prev, c_prev, W_ih, W_hh, b_lstm, ws);
  k_outproj_parse<<<134, 256, 0, stream>>>(W_out, b_out, ws);
  k_content<<<80, 1024, 0, stream>>>(memory, ws);
  k_write_path<<<16, 1024, 0, stream>>>(prw, pusage, pww, prec, ws, out);
  k_link<<<dim3(CHUNKS, BB), 512, 0, stream>>>(links, prw, memory, ws, out);
  k_readrw<<<128, 256, 0, stream>>>(memory, ws, out);
  k_final<<<16, 256, 0, stream>>>(W_read, b_read, ws, out);
}

// Round 5
// 224.721 us; speedup vs baseline: 1.1123x; 1.1123x over previous
//
#include <hip/hip_runtime.h>
#include <math.h>

// DNC single step, MI355X. All f32. B=16,N=2048,M=64,R=4,H=512.
constexpr int BB = 16, NN = 2048, MM = 64, RR = 4, HH = 512;
constexpr int CIN = 320, COUT = 535;
constexpr int CHUNKS = 64, ROWS = 32; // link kernel row-chunking (512 thr/block)

typedef float f32x4 __attribute__((ext_vector_type(4)));

// ---- output layout (floats): output, memory_new, link_new, p_new, usage, read_w
constexpr size_t O_OUT   = 0;
constexpr size_t O_MEM   = O_OUT + (size_t)BB * 64;
constexpr size_t O_LINK  = O_MEM + (size_t)BB * NN * MM;
constexpr size_t O_PNEW  = O_LINK + (size_t)BB * NN * NN;
constexpr size_t O_USAGE = O_PNEW + (size_t)BB * NN;
constexpr size_t O_READW = O_USAGE + (size_t)BB * NN;

// ---- workspace layout (floats)
constexpr size_t WS_H     = 0;                                   // B*512
constexpr size_t WS_OUTR  = WS_H + (size_t)BB * HH;              // B*535 (raw, for modes)
constexpr size_t WS_TASK  = WS_OUTR + (size_t)BB * COUT;         // B*64
constexpr size_t WS_RKEYS = WS_TASK + (size_t)BB * 64;           // B*256
constexpr size_t WS_RBETA = WS_RKEYS + (size_t)BB * 256;         // B*4
constexpr size_t WS_FGATE = WS_RBETA + (size_t)BB * 4;           // B*4
constexpr size_t WS_WKEY  = WS_FGATE + (size_t)BB * 4;           // B*64
constexpr size_t WS_WBETA = WS_WKEY + (size_t)BB * 64;           // B
constexpr size_t WS_ERASE = WS_WBETA + (size_t)BB;               // B*64
constexpr size_t WS_WVEC  = WS_ERASE + (size_t)BB * 64;          // B*64
constexpr size_t WS_AGATE = WS_WVEC + (size_t)BB * 64;           // B
constexpr size_t WS_WGATE = WS_AGATE + (size_t)BB;               // B
constexpr size_t WS_CONT  = WS_WGATE + (size_t)BB;               // B*5*N
constexpr size_t WS_WW    = WS_CONT + (size_t)BB * 5 * NN;       // B*N
constexpr size_t WS_FWD   = WS_WW + (size_t)BB * NN;             // B*4*N
constexpr size_t WS_BPART = WS_FWD + (size_t)BB * 4 * NN;        // B*CHUNKS*4*N
constexpr size_t WS_RPART = WS_BPART + (size_t)BB * CHUNKS * 4 * NN; // B*8*256
constexpr size_t WS_TOTAL = WS_RPART + (size_t)BB * 8 * 256;

__device__ __forceinline__ float sigf(float x) { return 1.0f / (1.0f + expf(-x)); }
__device__ __forceinline__ float oneplusf(float x) {
  return 1.0f + fmaxf(x, 0.0f) + log1pf(expf(-fabsf(x)));
}

// ---- K1: LSTM gates + cell fused. One block per hidden index j.
__global__ void k_gates_lstm(const float* __restrict__ task, const float* __restrict__ prev_reads,
                             const float* __restrict__ h_prev, const float* __restrict__ c_prev,
                             const float* __restrict__ W_ih, const float* __restrict__ W_hh,
                             const float* __restrict__ b_lstm, float* __restrict__ ws) {
  int tid = threadIdx.x, lane = tid & 63, wave = tid >> 6;
  int j = blockIdx.x;            // 0..511
  int row = wave * HH + j;       // gate row in [0,2048)
  __shared__ float gv[4][16];
  float acc[16];
#pragma unroll
  for (int b = 0; b < 16; b++) acc[b] = 0.f;
#pragma unroll
  for (int s = 0; s < 5; s++) {
    int k = s * 64 + lane;
    float wv = W_ih[(size_t)row * CIN + k];
    if (s == 0) {
#pragma unroll
      for (int b = 0; b < 16; b++) acc[b] += wv * task[b * 64 + k];
    } else {
#pragma unroll
      for (int b = 0; b < 16; b++) acc[b] += wv * prev_reads[b * 256 + (k - 64)];
    }
  }
#pragma unroll
  for (int s = 0; s < 8; s++) {
    int k = s * 64 + lane;
    float wv = W_hh[(size_t)row * HH + k];
#pragma unroll
    for (int b = 0; b < 16; b++) acc[b] += wv * h_prev[b * HH + k];
  }
#pragma unroll
  for (int b = 0; b < 16; b++) {
#pragma unroll
    for (int off = 32; off >= 1; off >>= 1) acc[b] += __shfl_xor(acc[b], off);
  }
  float val = 0.f;
#pragma unroll
  for (int b = 0; b < 16; b++) if (lane == b) val = acc[b];
  if (lane < 16) gv[wave][lane] = val + b_lstm[row];
  __syncthreads();
  if (tid < 16) {
    int b = tid;
    float gi = gv[0][b], gf = gv[1][b], gg = gv[2][b], go = gv[3][b];
    float c = sigf(gf) * c_prev[b * HH + j] + sigf(gi) * tanhf(gg);
    ws[WS_H + (size_t)b * HH + j] = sigf(go) * tanhf(c);
  }
}

// ---- K2: out_raw = h @ W_out^T + b_out, fused parse (one wave per row j<535)
__global__ void k_outproj_parse(const float* __restrict__ W_out, const float* __restrict__ b_out,
                                float* __restrict__ ws) {
  int tid = threadIdx.x, lane = tid & 63, wave = tid >> 6;
  int j = blockIdx.x * 4 + wave;
  if (j >= COUT) return;
  float acc[16];
#pragma unroll
  for (int b = 0; b < 16; b++) acc[b] = 0.f;
#pragma unroll
  for (int s = 0; s < 8; s++) {
    int k = s * 64 + lane;
    float wv = W_out[j * HH + k];
#pragma unroll
    for (int b = 0; b < 16; b++) acc[b] += wv * ws[WS_H + (size_t)b * HH + k];
  }
#pragma unroll
  for (int b = 0; b < 16; b++) {
#pragma unroll
    for (int off = 32; off >= 1; off >>= 1) acc[b] += __shfl_xor(acc[b], off);
  }
  float bias = b_out[j];
  float val = 0.f;
#pragma unroll
  for (int b = 0; b < 16; b++) if (lane == b) val = acc[b];
  if (lane < 16) {
    int b = lane;
    float v = val + bias;
    ws[WS_OUTR + (size_t)b * COUT + j] = v; // raw kept for read-mode softmax
    if (j < 64)       ws[WS_TASK + b * 64 + j] = sigf(v);
    else if (j < 320) ws[WS_RKEYS + b * 256 + (j - 64)] = sigf(v);
    else if (j < 324) ws[WS_RBETA + b * 4 + (j - 320)] = oneplusf(v);
    else if (j < 328) ws[WS_FGATE + b * 4 + (j - 324)] = sigf(v);
    else if (j < 392) ws[WS_WKEY + b * 64 + (j - 328)] = sigf(v);
    else if (j == 392) ws[WS_WBETA + b] = oneplusf(v);
    else if (j < 457) ws[WS_ERASE + b * 64 + (j - 393)] = sigf(v);
    else if (j < 521) ws[WS_WVEC + b * 64 + (j - 457)] = sigf(v);
    else if (j == 521) ws[WS_AGATE + b] = sigf(v);
    else if (j == 522) ws[WS_WGATE + b] = sigf(v);
  }
}

// ---- K3: content scores + softmax, one block per (b,key) (fused)
__global__ void __launch_bounds__(1024) k_content(const float* __restrict__ memory,
                                                  float* __restrict__ ws) {
  int bk = blockIdx.x; // b*5+k
  int b = bk / 5, k = bk % 5;
  int t = threadIdx.x, lane = t & 63, wave = t >> 6;
  __shared__ __align__(16) float kb[64];
  __shared__ float sc[NN];
  __shared__ float red[16];
  __shared__ float skn, sbeta;
  if (t < 64) kb[t] = (k < 4) ? ws[WS_RKEYS + b * 256 + k * 64 + t] : ws[WS_WKEY + b * 64 + t];
  if (t == 64) sbeta = (k < 4) ? ws[WS_RBETA + b * 4 + k] : ws[WS_WBETA + b];
  __syncthreads();
  if (wave == 0) {
    float kv = kb[lane];
    float ss = kv * kv;
#pragma unroll
    for (int off = 32; off >= 1; off >>= 1) ss += __shfl_xor(ss, off);
    if (lane == 0) skn = sqrtf(ss);
  }
  __syncthreads();
  float kn = skn, beta = sbeta;
  int r = lane >> 4, c = lane & 15;
  float4 key4 = *reinterpret_cast<const float4*>(&kb[c * 4]);
  for (int i = 0; i < 32; i++) {
    int n = wave * 128 + i * 4 + r;
    float4 v = *reinterpret_cast<const float4*>(&memory[((size_t)b * NN + n) * MM + c * 4]);
    float d = v.x * key4.x + v.y * key4.y + v.z * key4.z + v.w * key4.w;
    float s2 = v.x * v.x + v.y * v.y + v.z * v.z + v.w * v.w;
#pragma unroll
    for (int off = 1; off <= 8; off <<= 1) {
      d += __shfl_xor(d, off);
      s2 += __shfl_xor(s2, off);
    }
    if (c == 0) sc[n] = beta * d / (kn * sqrtf(s2) + 1e-8f);
  }
  __syncthreads();
  float v0 = sc[t], v1 = sc[t + 1024];
  float mx = fmaxf(v0, v1);
#pragma unroll
  for (int off = 32; off >= 1; off >>= 1) mx = fmaxf(mx, __shfl_xor(mx, off));
  if (lane == 0) red[wave] = mx;
  __syncthreads();
  mx = red[0];
  for (int w2 = 1; w2 < 16; w2++) mx = fmaxf(mx, red[w2]);
  float e0 = expf(v0 - mx), e1 = expf(v1 - mx);
  float s = e0 + e1;
#pragma unroll
  for (int off = 32; off >= 1; off >>= 1) s += __shfl_xor(s, off);
  __syncthreads();
  if (lane == 0) red[wave] = s;
  __syncthreads();
  s = 0.f;
  for (int w2 = 0; w2 < 16; w2++) s += red[w2];
  float inv = 1.f / s;
  float* dst = ws + WS_CONT + (size_t)bk * NN;
  dst[t] = e0 * inv;
  dst[t + 1024] = e1 * inv;
}

// ---- K4: usage + allocation + write weights + p_new, one block per b.
// Hybrid bitonic sort: thread t holds elements (2t, 2t+1) in registers; stages with
// distance j<=64 use in-wave shuffles (no barrier), j>=128 go through LDS.
// Comparator identical to the pure-LDS version -> same permutation.
__global__ void __launch_bounds__(1024) k_write_path(
    const float* __restrict__ prw, const float* __restrict__ pu,
    const float* __restrict__ pww, const float* __restrict__ prec,
    float* __restrict__ ws, float* __restrict__ out) {
  int b = blockIdx.x, t = threadIdx.x, lane = t & 63, wave = t >> 6;
  __shared__ float sv[NN];
  __shared__ int si[NN];
  __shared__ float al[NN];
  __shared__ float wred[16];
  float fg[4];
#pragma unroll
  for (int r = 0; r < 4; r++) fg[r] = ws[WS_FGATE + b * 4 + r];
  // usage for elements 2t, 2t+1 (float2 coalesced)
  float v0, v1; int i0_, i1_;
  {
    int n = 2 * t;
    float2 a2 = *reinterpret_cast<const float2*>(&pu[(size_t)b * NN + n]);
    float2 w2 = *reinterpret_cast<const float2*>(&pww[(size_t)b * NN + n]);
    float psi0 = 1.f, psi1 = 1.f;
#pragma unroll
    for (int r = 0; r < 4; r++) {
      float2 p2 = *reinterpret_cast<const float2*>(&prw[((size_t)b * 4 + r) * NN + n]);
      psi0 *= (1.f - fg[r] * p2.x);
      psi1 *= (1.f - fg[r] * p2.y);
    }
    v0 = (a2.x + w2.x - a2.x * w2.x) * psi0;
    v1 = (a2.y + w2.y - a2.y * w2.y) * psi1;
    float2 u2; u2.x = v0; u2.y = v1;
    *reinterpret_cast<float2*>(&out[O_USAGE + (size_t)b * NN + n]) = u2;
    i0_ = n; i1_ = n + 1;
  }

  // in-thread compare-exchange (distance j==1)
  auto cmp_in = [&](int k) {
    bool up = ((t & (k >> 1)) == 0);
    bool less10 = (v1 < v0) || (v1 == v0 && i1_ < i0_);
    if (up ? less10 : !less10) {
      float tv = v0; v0 = v1; v1 = tv;
      int ti = i0_; i0_ = i1_; i1_ = ti;
    }
  };
  // shuffle compare-exchange (distance 2<=j<=64; partner lane = lane ^ (j>>1))
  auto shfl_stage = [&](int j, int k) {
    int m = j >> 1;
    float pv0 = __shfl_xor(v0, m), pv1 = __shfl_xor(v1, m);
    int pi0 = __shfl_xor(i0_, m), pi1 = __shfl_xor(i1_, m);
    bool lower = ((t & m) == 0);
    bool up = ((t & (k >> 1)) == 0);
    bool lessP0 = (pv0 < v0) || (pv0 == v0 && pi0 < i0_);
    if (up ? (lower ? lessP0 : !lessP0) : (lower ? !lessP0 : lessP0)) { v0 = pv0; i0_ = pi0; }
    bool lessP1 = (pv1 < v1) || (pv1 == v1 && pi1 < i1_);
    if (up ? (lower ? lessP1 : !lessP1) : (lower ? !lessP1 : lessP1)) { v1 = pv1; i1_ = pi1; }
  };
  // LDS stages: j from jhi down to 128, then reload regs
  auto lds_stages = [&](int k, int jhi) {
    sv[2 * t] = v0; si[2 * t] = i0_; sv[2 * t + 1] = v1; si[2 * t + 1] = i1_;
    __syncthreads();
    for (int j = jhi; j >= 128; j >>= 1) {
#pragma unroll
      for (int e = 0; e < 2; e++) {
        int idx = t + e * 1024;
        int l = idx ^ j;
        if (l > idx) {
          bool up = ((idx & k) == 0);
          float va = sv[idx], vb = sv[l];
          int ia = si[idx], ib = si[l];
          bool lessBA = (vb < va) || (vb == va && ib < ia);
          if (up ? lessBA : !lessBA) { sv[idx] = vb; sv[l] = va; si[idx] = ib; si[l] = ia; }
        }
      }
      __syncthreads();
    }
    v0 = sv[2 * t]; i0_ = si[2 * t]; v1 = sv[2 * t + 1]; i1_ = si[2 * t + 1];
  };

  // k = 2..128: all stages in registers/shuffles, zero barriers
#pragma unroll
  for (int kk = 1; kk <= 7; kk++) {
    int k = 1 << kk;
#pragma unroll 6
    for (int j = k >> 1; j >= 2; j >>= 1) shfl_stage(j, k);
    cmp_in(k);
  }
  // k = 256..2048: LDS for j>=128, shuffles below
  lds_stages(256, 128);
#pragma unroll 6
  for (int j = 64; j >= 2; j >>= 1) shfl_stage(j, 256);
  cmp_in(256);
  lds_stages(512, 256);
#pragma unroll 6
  for (int j = 64; j >= 2; j >>= 1) shfl_stage(j, 512);
  cmp_in(512);
  lds_stages(1024, 512);
#pragma unroll 6
  for (int j = 64; j >= 2; j >>= 1) shfl_stage(j, 1024);
  cmp_in(1024);
  lds_stages(2048, 1024);
#pragma unroll 6
  for (int j = 64; j >= 2; j >>= 1) shfl_stage(j, 2048);
  cmp_in(2048);

  // exclusive cumprod over sorted values (thread owns sorted elems 2t, 2t+1)
  float lp = v0 * v1;
  float x = lp;
#pragma unroll
  for (int off = 1; off < 64; off <<= 1) {
    float y = __shfl_up(x, off);
    if (lane >= off) x *= y;
  }
  if (lane == 63) wred[wave] = x;
  float ex = __shfl_up(x, 1);
  if (lane == 0) ex = 1.f;
  __syncthreads();
  float base = 1.f;
  for (int w2 = 0; w2 < wave; w2++) base *= wred[w2];
  float E = base * ex;
  al[i0_] = (1.f - v0) * E;
  E *= v0;
  al[i1_] = (1.f - v1) * E;
  __syncthreads();
  float ag = ws[WS_AGATE + b], wg = ws[WS_WGATE + b];
  float wwv[2], ssum = 0.f;
#pragma unroll
  for (int e = 0; e < 2; e++) {
    int n = t + e * 1024;
    float cw = ws[WS_CONT + ((size_t)b * 5 + 4) * NN + n];
    wwv[e] = wg * (ag * al[n] + (1.f - ag) * cw);
    ws[WS_WW + (size_t)b * NN + n] = wwv[e];
    ssum += wwv[e];
  }
#pragma unroll
  for (int off = 32; off >= 1; off >>= 1) ssum += __shfl_xor(ssum, off);
  __syncthreads();
  if (lane == 0) wred[wave] = ssum;
  __syncthreads();
  float tot = 0.f;
  for (int w2 = 0; w2 < 16; w2++) tot += wred[w2];
  float om = 1.f - tot;
#pragma unroll
  for (int e = 0; e < 2; e++) {
    int n = t + e * 1024;
    out[O_PNEW + (size_t)b * NN + n] = om * prec[(size_t)b * NN + n] + wwv[e];
  }
}

// ---- K5: fused streaming pass over L: fwd_w, bwd partials, link_new, memory_new.
// 512 threads (8 waves), one full 8KB row per iteration, nontemporal L/link traffic.
// (R3 version — the R4 prefetch ring regressed; reverted.)
__global__ void __launch_bounds__(512) k_link(const float* __restrict__ L,
                                              const float* __restrict__ wprev,
                                              const float* __restrict__ mem,
                                              float* __restrict__ ws, float* __restrict__ out) {
  int b = blockIdx.y, chunk = blockIdx.x;
  int i0 = chunk * ROWS;
  int tid = threadIdx.x, lane = tid & 63, wave = tid >> 6; // 8 waves
  __shared__ float wwrow[ROWS];
  __shared__ float wprow[4][ROWS];
  __shared__ float fpart[8][4][ROWS]; // 4 KB
  if (tid < ROWS) wwrow[tid] = ws[WS_WW + (size_t)b * NN + i0 + tid];
  if (tid >= 64 && tid < 64 + 4 * ROWS) {
    int r = (tid - 64) >> 5, ii = (tid - 64) & 31;
    wprow[r][ii] = wprev[((size_t)b * 4 + r) * NN + i0 + ii];
  }
  int j = tid * 4; // fixed 4 columns per thread
  f32x4 wp[4], pn, wwj;
#pragma unroll
  for (int r = 0; r < 4; r++)
    wp[r] = *reinterpret_cast<const f32x4*>(&wprev[((size_t)b * 4 + r) * NN + j]);
  pn = *reinterpret_cast<const f32x4*>(&out[O_PNEW + (size_t)b * NN + j]);
  wwj = *reinterpret_cast<const f32x4*>(&ws[WS_WW + (size_t)b * NN + j]);
  __syncthreads();
  // fused memory_new for rows i0..i0+ROWS-1 (ROWS*64 = 2048 elems)
#pragma unroll
  for (int e = 0; e < 4; e++) {
    int idx = e * 512 + tid;
    int ii = idx >> 6, m = idx & 63;
    size_t g = ((size_t)b * NN + i0 + ii) * MM + m;
    float wwv = wwrow[ii];
    out[O_MEM + g] = mem[g] * (1.f - wwv * ws[WS_ERASE + b * 64 + m]) + wwv * ws[WS_WVEC + b * 64 + m];
  }
  f32x4 bacc[4];
#pragma unroll
  for (int r = 0; r < 4; r++) bacc[r] = (f32x4)(0.f);
  const float* Lb = L + (size_t)b * NN * NN;
  float* linkb = out + O_LINK + (size_t)b * NN * NN;
  for (int ii = 0; ii < ROWS; ii++) {
    int i = i0 + ii;
    const f32x4* lr = reinterpret_cast<const f32x4*>(Lb + (size_t)i * NN);
    f32x4 v = __builtin_nontemporal_load(lr + tid);
    // fwd partial dots (per-wave 256-column slice), reduce across 64 lanes
    float f0 = v[0] * wp[0][0] + v[1] * wp[0][1] + v[2] * wp[0][2] + v[3] * wp[0][3];
    float f1 = v[0] * wp[1][0] + v[1] * wp[1][1] + v[2] * wp[1][2] + v[3] * wp[1][3];
    float f2 = v[0] * wp[2][0] + v[1] * wp[2][1] + v[2] * wp[2][2] + v[3] * wp[2][3];
    float f3 = v[0] * wp[3][0] + v[1] * wp[3][1] + v[2] * wp[3][2] + v[3] * wp[3][3];
#pragma unroll
    for (int off = 32; off >= 1; off >>= 1) {
      f0 += __shfl_xor(f0, off);
      f1 += __shfl_xor(f1, off);
      f2 += __shfl_xor(f2, off);
      f3 += __shfl_xor(f3, off);
    }
    if (lane == 0) {
      fpart[wave][0][ii] = f0; fpart[wave][1][ii] = f1;
      fpart[wave][2][ii] = f2; fpart[wave][3][ii] = f3;
    }
    // bwd: column accumulation
#pragma unroll
    for (int r = 0; r < 4; r++) {
      float w = wprow[r][ii];
      bacc[r][0] += w * v[0]; bacc[r][1] += w * v[1];
      bacc[r][2] += w * v[2]; bacc[r][3] += w * v[3];
    }
    // link update + diagonal zero
    float wwi = wwrow[ii];
    f32x4 o;
    o[0] = (1.f - wwi - wwj[0]) * v[0] + wwi * pn[0];
    o[1] = (1.f - wwi - wwj[1]) * v[1] + wwi * pn[1];
    o[2] = (1.f - wwi - wwj[2]) * v[2] + wwi * pn[2];
    o[3] = (1.f - wwi - wwj[3]) * v[3] + wwi * pn[3];
    if (i == j)     o[0] = 0.f;
    if (i == j + 1) o[1] = 0.f;
    if (i == j + 2) o[2] = 0.f;
    if (i == j + 3) o[3] = 0.f;
    __builtin_nontemporal_store(o, reinterpret_cast<f32x4*>(linkb + (size_t)i * NN) + tid);
  }
  __syncthreads();
  if (tid < 4 * ROWS) {
    int r = tid >> 5, ii = tid & 31;
    float s = 0.f;
#pragma unroll
    for (int w2 = 0; w2 < 8; w2++) s += fpart[w2][r][ii];
    ws[WS_FWD + ((size_t)b * 4 + r) * NN + i0 + ii] = s;
  }
#pragma unroll
  for (int r = 0; r < 4; r++)
    *reinterpret_cast<f32x4*>(
        &ws[WS_BPART + (((size_t)b * CHUNKS + chunk) * 4 + r) * NN + j]) = bacc[r];
}

// ---- K6: bwd chunk-reduce + read modes + read_w + read partial dots (fused)
__global__ void __launch_bounds__(256) k_readrw(const float* __restrict__ memory,
                                                float* __restrict__ ws, float* __restrict__ out) {
  int b = blockIdx.x >> 3, chunk = blockIdx.x & 7;
  int n0 = chunk * 256;
  int t = threadIdx.x, lane = t & 63, wave = t >> 6;
  __shared__ float fm[4][3];
  __shared__ float rwl[4][256];
  __shared__ float part[4][4][64];
  if (t < 4) {
    const float* o = ws + WS_OUTR + (size_t)b * COUT + 523 + t * 3;
    float a = o[0], bb = o[1], cc = o[2];
    float m = fmaxf(a, fmaxf(bb, cc));
    float ea = expf(a - m), eb = expf(bb - m), ec = expf(cc - m);
    float iv = 1.f / (ea + eb + ec);
    fm[t][0] = ea * iv; fm[t][1] = eb * iv; fm[t][2] = ec * iv;
  }
  __syncthreads();
#pragma unroll
  for (int r = 0; r < 4; r++) {
    int n = n0 + t;
    float bwd = 0.f;
    for (int c2 = 0; c2 < CHUNKS; c2++)
      bwd += ws[WS_BPART + (((size_t)b * CHUNKS + c2) * 4 + r) * NN + n];
    float fwd = ws[WS_FWD + ((size_t)b * 4 + r) * NN + n];
    float cont = ws[WS_CONT + ((size_t)b * 5 + r) * NN + n];
    float rw = fm[r][0] * bwd + fm[r][1] * cont + fm[r][2] * fwd;
    out[O_READW + ((size_t)b * 4 + r) * NN + n] = rw;
    rwl[r][t] = rw;
  }
  __syncthreads();
  float acc[4] = {0.f, 0.f, 0.f, 0.f};
  for (int ii = 0; ii < 64; ii++) {
    int nl = wave * 64 + ii;
    float mv = memory[((size_t)b * NN + n0 + nl) * MM + lane];
#pragma unroll
    for (int r = 0; r < 4; r++) acc[r] += rwl[r][nl] * mv;
  }
#pragma unroll
  for (int r = 0; r < 4; r++) part[wave][r][lane] = acc[r];
  __syncthreads();
  { int r = t >> 6, m = t & 63;
    float s = part[0][r][m] + part[1][r][m] + part[2][r][m] + part[3][r][m];
    ws[WS_RPART + ((size_t)(b * 8 + chunk)) * 256 + t] = s; }
}

// ---- K7: reduce read partials + read projection + final output
__global__ void k_final(const float* __restrict__ W_read, const float* __restrict__ b_read,
                        const float* __restrict__ ws, float* __restrict__ out) {
  int b = blockIdx.x, t = threadIdx.x, lane = t & 63, wave = t >> 6;
  __shared__ float rds[256];
  float s = 0.f;
  for (int c = 0; c < 8; c++) s += ws[WS_RPART + ((size_t)(b * 8 + c)) * 256 + t];
  rds[t] = s;
  __syncthreads();
  for (int oi = 0; oi < 16; oi++) {
    int o = wave * 16 + oi;
    float acc = 0.f;
#pragma unroll
    for (int s2 = 0; s2 < 4; s2++) {
      int kk = s2 * 64 + lane;
      acc += W_read[o * 256 + kk] * rds[kk];
    }
#pragma unroll
    for (int off = 32; off >= 1; off >>= 1) acc += __shfl_xor(acc, off);
    if (lane == 0) {
      float ro = sigf(acc + b_read[o]);
      out[O_OUT + b * 64 + o] = sigf(ro + ws[WS_TASK + b * 64 + o]);
    }
  }
}

extern "C" void kernel_launch(void* const* d_in, const int* in_sizes, int n_in,
                              void* d_out, int out_size, void* d_ws, size_t ws_size,
                              hipStream_t stream) {
  (void)in_sizes; (void)n_in; (void)out_size; (void)ws_size;
  const float* task   = (const float*)d_in[0];
  const float* memory = (const float*)d_in[1];
  const float* links  = (const float*)d_in[2];
  const float* preads = (const float*)d_in[3];
  const float* prw    = (const float*)d_in[4];
  const float* pusage = (const float*)d_in[5];
  const float* pww    = (const float*)d_in[6];
  const float* prec   = (const float*)d_in[7];
  const float* h_prev = (const float*)d_in[8];
  const float* c_prev = (const float*)d_in[9];
  const float* W_ih   = (const float*)d_in[10];
  const float* W_hh   = (const float*)d_in[11];
  const float* b_lstm = (const float*)d_in[12];
  const float* W_out  = (const float*)d_in[13];
  const float* b_out  = (const float*)d_in[14];
  const float* W_read = (const float*)d_in[15];
  const float* b_read = (const float*)d_in[16];
  float* out = (float*)d_out;
  float* ws  = (float*)d_ws;

  k_gates_lstm<<<512, 256, 0, stream>>>(task, preads, h_prev, c_prev, W_ih, W_hh, b_lstm, ws);
  k_outproj_parse<<<134, 256, 0, stream>>>(W_out, b_out, ws);
  k_content<<<80, 1024, 0, stream>>>(memory, ws);
  k_write_path<<<16, 1024, 0, stream>>>(prw, pusage, pww, prec, ws, out);
  k_link<<<dim3(CHUNKS, BB), 512, 0, stream>>>(links, prw, memory, ws, out);
  k_readrw<<<128, 256, 0, stream>>>(memory, ws, out);
  k_final<<<16, 256, 0, stream>>>(W_read, b_read, ws, out);
}

// Round 6
// 209.369 us; speedup vs baseline: 1.1939x; 1.0733x over previous
//
#include <hip/hip_runtime.h>
#include <math.h>

// DNC single step, MI355X. All f32. B=16,N=2048,M=64,R=4,H=512.
constexpr int BB = 16, NN = 2048, MM = 64, RR = 4, HH = 512;
constexpr int CIN = 320, COUT = 535;
constexpr int CHUNKS = 64, ROWS = 32; // link kernel row-chunking (512 thr/block)

typedef float f32x4 __attribute__((ext_vector_type(4)));

// ---- output layout (floats): output, memory_new, link_new, p_new, usage, read_w
constexpr size_t O_OUT   = 0;
constexpr size_t O_MEM   = O_OUT + (size_t)BB * 64;
constexpr size_t O_LINK  = O_MEM + (size_t)BB * NN * MM;
constexpr size_t O_PNEW  = O_LINK + (size_t)BB * NN * NN;
constexpr size_t O_USAGE = O_PNEW + (size_t)BB * NN;
constexpr size_t O_READW = O_USAGE + (size_t)BB * NN;

// ---- workspace layout (floats)
constexpr size_t WS_H     = 0;                                   // B*512
constexpr size_t WS_OUTR  = WS_H + (size_t)BB * HH;              // B*535 (raw, for modes)
constexpr size_t WS_TASK  = WS_OUTR + (size_t)BB * COUT;         // B*64
constexpr size_t WS_RKEYS = WS_TASK + (size_t)BB * 64;           // B*256
constexpr size_t WS_RBETA = WS_RKEYS + (size_t)BB * 256;         // B*4
constexpr size_t WS_FGATE = WS_RBETA + (size_t)BB * 4;           // B*4
constexpr size_t WS_WKEY  = WS_FGATE + (size_t)BB * 4;           // B*64
constexpr size_t WS_WBETA = WS_WKEY + (size_t)BB * 64;           // B
constexpr size_t WS_ERASE = WS_WBETA + (size_t)BB;               // B*64
constexpr size_t WS_WVEC  = WS_ERASE + (size_t)BB * 64;          // B*64
constexpr size_t WS_AGATE = WS_WVEC + (size_t)BB * 64;           // B
constexpr size_t WS_WGATE = WS_AGATE + (size_t)BB;               // B
constexpr size_t WS_CONT  = WS_WGATE + (size_t)BB;               // B*5*N
constexpr size_t WS_WW    = WS_CONT + (size_t)BB * 5 * NN;       // B*N
constexpr size_t WS_FWD   = WS_WW + (size_t)BB * NN;             // B*4*N
constexpr size_t WS_BPART = WS_FWD + (size_t)BB * 4 * NN;        // B*CHUNKS*4*N
constexpr size_t WS_RPART = WS_BPART + (size_t)BB * CHUNKS * 4 * NN; // B*8*256
constexpr size_t WS_TOTAL = WS_RPART + (size_t)BB * 8 * 256;

__device__ __forceinline__ float sigf(float x) { return 1.0f / (1.0f + expf(-x)); }
__device__ __forceinline__ float oneplusf(float x) {
  return 1.0f + fmaxf(x, 0.0f) + log1pf(expf(-fabsf(x)));
}

// ---- K1: LSTM gates + cell fused. One block per hidden index j.
__global__ void k_gates_lstm(const float* __restrict__ task, const float* __restrict__ prev_reads,
                             const float* __restrict__ h_prev, const float* __restrict__ c_prev,
                             const float* __restrict__ W_ih, const float* __restrict__ W_hh,
                             const float* __restrict__ b_lstm, float* __restrict__ ws) {
  int tid = threadIdx.x, lane = tid & 63, wave = tid >> 6;
  int j = blockIdx.x;            // 0..511
  int row = wave * HH + j;       // gate row in [0,2048)
  __shared__ float gv[4][16];
  float acc[16];
#pragma unroll
  for (int b = 0; b < 16; b++) acc[b] = 0.f;
#pragma unroll
  for (int s = 0; s < 5; s++) {
    int k = s * 64 + lane;
    float wv = W_ih[(size_t)row * CIN + k];
    if (s == 0) {
#pragma unroll
      for (int b = 0; b < 16; b++) acc[b] += wv * task[b * 64 + k];
    } else {
#pragma unroll
      for (int b = 0; b < 16; b++) acc[b] += wv * prev_reads[b * 256 + (k - 64)];
    }
  }
#pragma unroll
  for (int s = 0; s < 8; s++) {
    int k = s * 64 + lane;
    float wv = W_hh[(size_t)row * HH + k];
#pragma unroll
    for (int b = 0; b < 16; b++) acc[b] += wv * h_prev[b * HH + k];
  }
#pragma unroll
  for (int b = 0; b < 16; b++) {
#pragma unroll
    for (int off = 32; off >= 1; off >>= 1) acc[b] += __shfl_xor(acc[b], off);
  }
  float val = 0.f;
#pragma unroll
  for (int b = 0; b < 16; b++) if (lane == b) val = acc[b];
  if (lane < 16) gv[wave][lane] = val + b_lstm[row];
  __syncthreads();
  if (tid < 16) {
    int b = tid;
    float gi = gv[0][b], gf = gv[1][b], gg = gv[2][b], go = gv[3][b];
    float c = sigf(gf) * c_prev[b * HH + j] + sigf(gi) * tanhf(gg);
    ws[WS_H + (size_t)b * HH + j] = sigf(go) * tanhf(c);
  }
}

// ---- K2: out_raw = h @ W_out^T + b_out, fused parse (one wave per row j<535)
__global__ void k_outproj_parse(const float* __restrict__ W_out, const float* __restrict__ b_out,
                                float* __restrict__ ws) {
  int tid = threadIdx.x, lane = tid & 63, wave = tid >> 6;
  int j = blockIdx.x * 4 + wave;
  if (j >= COUT) return;
  float acc[16];
#pragma unroll
  for (int b = 0; b < 16; b++) acc[b] = 0.f;
#pragma unroll
  for (int s = 0; s < 8; s++) {
    int k = s * 64 + lane;
    float wv = W_out[j * HH + k];
#pragma unroll
    for (int b = 0; b < 16; b++) acc[b] += wv * ws[WS_H + (size_t)b * HH + k];
  }
#pragma unroll
  for (int b = 0; b < 16; b++) {
#pragma unroll
    for (int off = 32; off >= 1; off >>= 1) acc[b] += __shfl_xor(acc[b], off);
  }
  float bias = b_out[j];
  float val = 0.f;
#pragma unroll
  for (int b = 0; b < 16; b++) if (lane == b) val = acc[b];
  if (lane < 16) {
    int b = lane;
    float v = val + bias;
    ws[WS_OUTR + (size_t)b * COUT + j] = v; // raw kept for read-mode softmax
    if (j < 64)       ws[WS_TASK + b * 64 + j] = sigf(v);
    else if (j < 320) ws[WS_RKEYS + b * 256 + (j - 64)] = sigf(v);
    else if (j < 324) ws[WS_RBETA + b * 4 + (j - 320)] = oneplusf(v);
    else if (j < 328) ws[WS_FGATE + b * 4 + (j - 324)] = sigf(v);
    else if (j < 392) ws[WS_WKEY + b * 64 + (j - 328)] = sigf(v);
    else if (j == 392) ws[WS_WBETA + b] = oneplusf(v);
    else if (j < 457) ws[WS_ERASE + b * 64 + (j - 393)] = sigf(v);
    else if (j < 521) ws[WS_WVEC + b * 64 + (j - 457)] = sigf(v);
    else if (j == 521) ws[WS_AGATE + b] = sigf(v);
    else if (j == 522) ws[WS_WGATE + b] = sigf(v);
  }
}

// ---- K3: content scores + softmax, one block per (b,key) (fused)
__global__ void __launch_bounds__(1024) k_content(const float* __restrict__ memory,
                                                  float* __restrict__ ws) {
  int bk = blockIdx.x; // b*5+k
  int b = bk / 5, k = bk % 5;
  int t = threadIdx.x, lane = t & 63, wave = t >> 6;
  __shared__ __align__(16) float kb[64];
  __shared__ float sc[NN];
  __shared__ float red[16];
  __shared__ float skn, sbeta;
  if (t < 64) kb[t] = (k < 4) ? ws[WS_RKEYS + b * 256 + k * 64 + t] : ws[WS_WKEY + b * 64 + t];
  if (t == 64) sbeta = (k < 4) ? ws[WS_RBETA + b * 4 + k] : ws[WS_WBETA + b];
  __syncthreads();
  if (wave == 0) {
    float kv = kb[lane];
    float ss = kv * kv;
#pragma unroll
    for (int off = 32; off >= 1; off >>= 1) ss += __shfl_xor(ss, off);
    if (lane == 0) skn = sqrtf(ss);
  }
  __syncthreads();
  float kn = skn, beta = sbeta;
  int r = lane >> 4, c = lane & 15;
  float4 key4 = *reinterpret_cast<const float4*>(&kb[c * 4]);
  for (int i = 0; i < 32; i++) {
    int n = wave * 128 + i * 4 + r;
    float4 v = *reinterpret_cast<const float4*>(&memory[((size_t)b * NN + n) * MM + c * 4]);
    float d = v.x * key4.x + v.y * key4.y + v.z * key4.z + v.w * key4.w;
    float s2 = v.x * v.x + v.y * v.y + v.z * v.z + v.w * v.w;
#pragma unroll
    for (int off = 1; off <= 8; off <<= 1) {
      d += __shfl_xor(d, off);
      s2 += __shfl_xor(s2, off);
    }
    if (c == 0) sc[n] = beta * d / (kn * sqrtf(s2) + 1e-8f);
  }
  __syncthreads();
  float v0 = sc[t], v1 = sc[t + 1024];
  float mx = fmaxf(v0, v1);
#pragma unroll
  for (int off = 32; off >= 1; off >>= 1) mx = fmaxf(mx, __shfl_xor(mx, off));
  if (lane == 0) red[wave] = mx;
  __syncthreads();
  mx = red[0];
  for (int w2 = 1; w2 < 16; w2++) mx = fmaxf(mx, red[w2]);
  float e0 = expf(v0 - mx), e1 = expf(v1 - mx);
  float s = e0 + e1;
#pragma unroll
  for (int off = 32; off >= 1; off >>= 1) s += __shfl_xor(s, off);
  __syncthreads();
  if (lane == 0) red[wave] = s;
  __syncthreads();
  s = 0.f;
  for (int w2 = 0; w2 < 16; w2++) s += red[w2];
  float inv = 1.f / s;
  float* dst = ws + WS_CONT + (size_t)bk * NN;
  dst[t] = e0 * inv;
  dst[t + 1024] = e1 * inv;
}

// ---- K4: usage + allocation + write weights + p_new, one block per b.
// Hybrid bitonic sort (registers/shuffles for j<=64, LDS for j>=128).
__global__ void __launch_bounds__(1024) k_write_path(
    const float* __restrict__ prw, const float* __restrict__ pu,
    const float* __restrict__ pww, const float* __restrict__ prec,
    float* __restrict__ ws, float* __restrict__ out) {
  int b = blockIdx.x, t = threadIdx.x, lane = t & 63, wave = t >> 6;
  __shared__ float sv[NN];
  __shared__ int si[NN];
  __shared__ float al[NN];
  __shared__ float wred[16];
  float fg[4];
#pragma unroll
  for (int r = 0; r < 4; r++) fg[r] = ws[WS_FGATE + b * 4 + r];
  float v0, v1; int i0_, i1_;
  {
    int n = 2 * t;
    float2 a2 = *reinterpret_cast<const float2*>(&pu[(size_t)b * NN + n]);
    float2 w2 = *reinterpret_cast<const float2*>(&pww[(size_t)b * NN + n]);
    float psi0 = 1.f, psi1 = 1.f;
#pragma unroll
    for (int r = 0; r < 4; r++) {
      float2 p2 = *reinterpret_cast<const float2*>(&prw[((size_t)b * 4 + r) * NN + n]);
      psi0 *= (1.f - fg[r] * p2.x);
      psi1 *= (1.f - fg[r] * p2.y);
    }
    v0 = (a2.x + w2.x - a2.x * w2.x) * psi0;
    v1 = (a2.y + w2.y - a2.y * w2.y) * psi1;
    float2 u2; u2.x = v0; u2.y = v1;
    *reinterpret_cast<float2*>(&out[O_USAGE + (size_t)b * NN + n]) = u2;
    i0_ = n; i1_ = n + 1;
  }

  auto cmp_in = [&](int k) {
    bool up = ((t & (k >> 1)) == 0);
    bool less10 = (v1 < v0) || (v1 == v0 && i1_ < i0_);
    if (up ? less10 : !less10) {
      float tv = v0; v0 = v1; v1 = tv;
      int ti = i0_; i0_ = i1_; i1_ = ti;
    }
  };
  auto shfl_stage = [&](int j, int k) {
    int m = j >> 1;
    float pv0 = __shfl_xor(v0, m), pv1 = __shfl_xor(v1, m);
    int pi0 = __shfl_xor(i0_, m), pi1 = __shfl_xor(i1_, m);
    bool lower = ((t & m) == 0);
    bool up = ((t & (k >> 1)) == 0);
    bool lessP0 = (pv0 < v0) || (pv0 == v0 && pi0 < i0_);
    if (up ? (lower ? lessP0 : !lessP0) : (lower ? !lessP0 : lessP0)) { v0 = pv0; i0_ = pi0; }
    bool lessP1 = (pv1 < v1) || (pv1 == v1 && pi1 < i1_);
    if (up ? (lower ? lessP1 : !lessP1) : (lower ? !lessP1 : lessP1)) { v1 = pv1; i1_ = pi1; }
  };
  auto lds_stages = [&](int k, int jhi) {
    sv[2 * t] = v0; si[2 * t] = i0_; sv[2 * t + 1] = v1; si[2 * t + 1] = i1_;
    __syncthreads();
    for (int j = jhi; j >= 128; j >>= 1) {
#pragma unroll
      for (int e = 0; e < 2; e++) {
        int idx = t + e * 1024;
        int l = idx ^ j;
        if (l > idx) {
          bool up = ((idx & k) == 0);
          float va = sv[idx], vb = sv[l];
          int ia = si[idx], ib = si[l];
          bool lessBA = (vb < va) || (vb == va && ib < ia);
          if (up ? lessBA : !lessBA) { sv[idx] = vb; sv[l] = va; si[idx] = ib; si[l] = ia; }
        }
      }
      __syncthreads();
    }
    v0 = sv[2 * t]; i0_ = si[2 * t]; v1 = sv[2 * t + 1]; i1_ = si[2 * t + 1];
  };

#pragma unroll
  for (int kk = 1; kk <= 7; kk++) {
    int k = 1 << kk;
#pragma unroll 6
    for (int j = k >> 1; j >= 2; j >>= 1) shfl_stage(j, k);
    cmp_in(k);
  }
  lds_stages(256, 128);
#pragma unroll 6
  for (int j = 64; j >= 2; j >>= 1) shfl_stage(j, 256);
  cmp_in(256);
  lds_stages(512, 256);
#pragma unroll 6
  for (int j = 64; j >= 2; j >>= 1) shfl_stage(j, 512);
  cmp_in(512);
  lds_stages(1024, 512);
#pragma unroll 6
  for (int j = 64; j >= 2; j >>= 1) shfl_stage(j, 1024);
  cmp_in(1024);
  lds_stages(2048, 1024);
#pragma unroll 6
  for (int j = 64; j >= 2; j >>= 1) shfl_stage(j, 2048);
  cmp_in(2048);

  float lp = v0 * v1;
  float x = lp;
#pragma unroll
  for (int off = 1; off < 64; off <<= 1) {
    float y = __shfl_up(x, off);
    if (lane >= off) x *= y;
  }
  if (lane == 63) wred[wave] = x;
  float ex = __shfl_up(x, 1);
  if (lane == 0) ex = 1.f;
  __syncthreads();
  float base = 1.f;
  for (int w2 = 0; w2 < wave; w2++) base *= wred[w2];
  float E = base * ex;
  al[i0_] = (1.f - v0) * E;
  E *= v0;
  al[i1_] = (1.f - v1) * E;
  __syncthreads();
  float ag = ws[WS_AGATE + b], wg = ws[WS_WGATE + b];
  float wwv[2], ssum = 0.f;
#pragma unroll
  for (int e = 0; e < 2; e++) {
    int n = t + e * 1024;
    float cw = ws[WS_CONT + ((size_t)b * 5 + 4) * NN + n];
    wwv[e] = wg * (ag * al[n] + (1.f - ag) * cw);
    ws[WS_WW + (size_t)b * NN + n] = wwv[e];
    ssum += wwv[e];
  }
#pragma unroll
  for (int off = 32; off >= 1; off >>= 1) ssum += __shfl_xor(ssum, off);
  __syncthreads();
  if (lane == 0) wred[wave] = ssum;
  __syncthreads();
  float tot = 0.f;
  for (int w2 = 0; w2 < 16; w2++) tot += wred[w2];
  float om = 1.f - tot;
#pragma unroll
  for (int e = 0; e < 2; e++) {
    int n = t + e * 1024;
    out[O_PNEW + (size_t)b * NN + n] = om * prec[(size_t)b * NN + n] + wwv[e];
  }
}

// ---- K5: fused streaming pass over L: fwd_w, bwd partials, link_new, memory_new.
// 512 threads (8 waves). Fold-tree reduce: 7 shuffles for all 4 fwd dots
// (was 24 shuffles + 24 adds), diagonal-zero via rare branch (was 4 cndmask).
__global__ void __launch_bounds__(512) k_link(const float* __restrict__ L,
                                              const float* __restrict__ wprev,
                                              const float* __restrict__ mem,
                                              float* __restrict__ ws, float* __restrict__ out) {
  int b = blockIdx.y, chunk = blockIdx.x;
  int i0 = chunk * ROWS;
  int tid = threadIdx.x, lane = tid & 63, wave = tid >> 6; // 8 waves
  __shared__ float wwrow[ROWS];
  __shared__ float wprow[4][ROWS];
  __shared__ float fpart[8][4][ROWS]; // 4 KB
  if (tid < ROWS) wwrow[tid] = ws[WS_WW + (size_t)b * NN + i0 + tid];
  if (tid >= 64 && tid < 64 + 4 * ROWS) {
    int r = (tid - 64) >> 5, ii = (tid - 64) & 31;
    wprow[r][ii] = wprev[((size_t)b * 4 + r) * NN + i0 + ii];
  }
  int j = tid * 4; // fixed 4 columns per thread
  f32x4 wp[4], pn, wwj;
#pragma unroll
  for (int r = 0; r < 4; r++)
    wp[r] = *reinterpret_cast<const f32x4*>(&wprev[((size_t)b * 4 + r) * NN + j]);
  pn = *reinterpret_cast<const f32x4*>(&out[O_PNEW + (size_t)b * NN + j]);
  wwj = *reinterpret_cast<const f32x4*>(&ws[WS_WW + (size_t)b * NN + j]);
  __syncthreads();
  // fused memory_new for rows i0..i0+ROWS-1 (ROWS*64 = 2048 elems)
#pragma unroll
  for (int e = 0; e < 4; e++) {
    int idx = e * 512 + tid;
    int ii = idx >> 6, m = idx & 63;
    size_t g = ((size_t)b * NN + i0 + ii) * MM + m;
    float wwv = wwrow[ii];
    out[O_MEM + g] = mem[g] * (1.f - wwv * ws[WS_ERASE + b * 64 + m]) + wwv * ws[WS_WVEC + b * 64 + m];
  }
  f32x4 bacc[4];
#pragma unroll
  for (int r = 0; r < 4; r++) bacc[r] = (f32x4)(0.f);
  const float* Lb = L + (size_t)b * NN * NN;
  float* linkb = out + O_LINK + (size_t)b * NN * NN;
  bool hi32 = (lane & 32) != 0;
  bool hi16 = (lane & 16) != 0;
  // fpart row index for this lane's fold-tree slot (lanes 0,16,32,48 -> f0,f2,f1,f3)
  int g4 = lane >> 4;
  int rsel = ((g4 & 1) << 1) | (g4 >> 1); // {0,2,1,3}
  for (int ii = 0; ii < ROWS; ii++) {
    int i = i0 + ii;
    const f32x4* lr = reinterpret_cast<const f32x4*>(Lb + (size_t)i * NN);
    f32x4 v = __builtin_nontemporal_load(lr + tid);
    // fwd partial dots
    float f0 = v[0] * wp[0][0] + v[1] * wp[0][1] + v[2] * wp[0][2] + v[3] * wp[0][3];
    float f1 = v[0] * wp[1][0] + v[1] * wp[1][1] + v[2] * wp[1][2] + v[3] * wp[1][3];
    float f2 = v[0] * wp[2][0] + v[1] * wp[2][1] + v[2] * wp[2][2] + v[3] * wp[2][3];
    float f3 = v[0] * wp[3][0] + v[1] * wp[3][1] + v[2] * wp[3][2] + v[3] * wp[3][3];
    // fold-tree: pack 4 dots into lane quadrants, then shared reduce
    float u01 = (hi32 ? f1 : f0) + __shfl_xor(hi32 ? f0 : f1, 32);
    float u23 = (hi32 ? f3 : f2) + __shfl_xor(hi32 ? f2 : f3, 32);
    float w = (hi16 ? u23 : u01) + __shfl_xor(hi16 ? u01 : u23, 16);
    w += __shfl_xor(w, 8);
    w += __shfl_xor(w, 4);
    w += __shfl_xor(w, 2);
    w += __shfl_xor(w, 1);
    if ((lane & 15) == 0) fpart[wave][rsel][ii] = w;
    // bwd: column accumulation
#pragma unroll
    for (int r = 0; r < 4; r++) {
      float wr = wprow[r][ii];
      bacc[r][0] += wr * v[0]; bacc[r][1] += wr * v[1];
      bacc[r][2] += wr * v[2]; bacc[r][3] += wr * v[3];
    }
    // link update; diagonal zero via rare branch
    float wwi = wwrow[ii];
    f32x4 o;
    o[0] = (1.f - wwi - wwj[0]) * v[0] + wwi * pn[0];
    o[1] = (1.f - wwi - wwj[1]) * v[1] + wwi * pn[1];
    o[2] = (1.f - wwi - wwj[2]) * v[2] + wwi * pn[2];
    o[3] = (1.f - wwi - wwj[3]) * v[3] + wwi * pn[3];
    unsigned di = (unsigned)(i - j);
    if (di < 4u) {
      if (di == 0) o[0] = 0.f;
      else if (di == 1) o[1] = 0.f;
      else if (di == 2) o[2] = 0.f;
      else o[3] = 0.f;
    }
    __builtin_nontemporal_store(o, reinterpret_cast<f32x4*>(linkb + (size_t)i * NN) + tid);
  }
  __syncthreads();
  if (tid < 4 * ROWS) {
    int r = tid >> 5, ii = tid & 31;
    float s = 0.f;
#pragma unroll
    for (int w2 = 0; w2 < 8; w2++) s += fpart[w2][r][ii];
    ws[WS_FWD + ((size_t)b * 4 + r) * NN + i0 + ii] = s;
  }
#pragma unroll
  for (int r = 0; r < 4; r++)
    *reinterpret_cast<f32x4*>(
        &ws[WS_BPART + (((size_t)b * CHUNKS + chunk) * 4 + r) * NN + j]) = bacc[r];
}

// ---- K6: bwd chunk-reduce + read modes + read_w + read partial dots (fused)
__global__ void __launch_bounds__(256) k_readrw(const float* __restrict__ memory,
                                                float* __restrict__ ws, float* __restrict__ out) {
  int b = blockIdx.x >> 3, chunk = blockIdx.x & 7;
  int n0 = chunk * 256;
  int t = threadIdx.x, lane = t & 63, wave = t >> 6;
  __shared__ float fm[4][3];
  __shared__ float rwl[4][256];
  __shared__ float part[4][4][64];
  if (t < 4) {
    const float* o = ws + WS_OUTR + (size_t)b * COUT + 523 + t * 3;
    float a = o[0], bb = o[1], cc = o[2];
    float m = fmaxf(a, fmaxf(bb, cc));
    float ea = expf(a - m), eb = expf(bb - m), ec = expf(cc - m);
    float iv = 1.f / (ea + eb + ec);
    fm[t][0] = ea * iv; fm[t][1] = eb * iv; fm[t][2] = ec * iv;
  }
  __syncthreads();
#pragma unroll
  for (int r = 0; r < 4; r++) {
    int n = n0 + t;
    float bwd = 0.f;
    for (int c2 = 0; c2 < CHUNKS; c2++)
      bwd += ws[WS_BPART + (((size_t)b * CHUNKS + c2) * 4 + r) * NN + n];
    float fwd = ws[WS_FWD + ((size_t)b * 4 + r) * NN + n];
    float cont = ws[WS_CONT + ((size_t)b * 5 + r) * NN + n];
    float rw = fm[r][0] * bwd + fm[r][1] * cont + fm[r][2] * fwd;
    out[O_READW + ((size_t)b * 4 + r) * NN + n] = rw;
    rwl[r][t] = rw;
  }
  __syncthreads();
  float acc[4] = {0.f, 0.f, 0.f, 0.f};
  for (int ii = 0; ii < 64; ii++) {
    int nl = wave * 64 + ii;
    float mv = memory[((size_t)b * NN + n0 + nl) * MM + lane];
#pragma unroll
    for (int r = 0; r < 4; r++) acc[r] += rwl[r][nl] * mv;
  }
#pragma unroll
  for (int r = 0; r < 4; r++) part[wave][r][lane] = acc[r];
  __syncthreads();
  { int r = t >> 6, m = t & 63;
    float s = part[0][r][m] + part[1][r][m] + part[2][r][m] + part[3][r][m];
    ws[WS_RPART + ((size_t)(b * 8 + chunk)) * 256 + t] = s; }
}

// ---- K7: reduce read partials + read projection + final output
__global__ void k_final(const float* __restrict__ W_read, const float* __restrict__ b_read,
                        const float* __restrict__ ws, float* __restrict__ out) {
  int b = blockIdx.x, t = threadIdx.x, lane = t & 63, wave = t >> 6;
  __shared__ float rds[256];
  float s = 0.f;
  for (int c = 0; c < 8; c++) s += ws[WS_RPART + ((size_t)(b * 8 + c)) * 256 + t];
  rds[t] = s;
  __syncthreads();
  for (int oi = 0; oi < 16; oi++) {
    int o = wave * 16 + oi;
    float acc = 0.f;
#pragma unroll
    for (int s2 = 0; s2 < 4; s2++) {
      int kk = s2 * 64 + lane;
      acc += W_read[o * 256 + kk] * rds[kk];
    }
#pragma unroll
    for (int off = 32; off >= 1; off >>= 1) acc += __shfl_xor(acc, off);
    if (lane == 0) {
      float ro = sigf(acc + b_read[o]);
      out[O_OUT + b * 64 + o] = sigf(ro + ws[WS_TASK + b * 64 + o]);
    }
  }
}

extern "C" void kernel_launch(void* const* d_in, const int* in_sizes, int n_in,
                              void* d_out, int out_size, void* d_ws, size_t ws_size,
                              hipStream_t stream) {
  (void)in_sizes; (void)n_in; (void)out_size; (void)ws_size;
  const float* task   = (const float*)d_in[0];
  const float* memory = (const float*)d_in[1];
  const float* links  = (const float*)d_in[2];
  const float* preads = (const float*)d_in[3];
  const float* prw    = (const float*)d_in[4];
  const float* pusage = (const float*)d_in[5];
  const float* pww    = (const float*)d_in[6];
  const float* prec   = (const float*)d_in[7];
  const float* h_prev = (const float*)d_in[8];
  const float* c_prev = (const float*)d_in[9];
  const float* W_ih   = (const float*)d_in[10];
  const float* W_hh   = (const float*)d_in[11];
  const float* b_lstm = (const float*)d_in[12];
  const float* W_out  = (const float*)d_in[13];
  const float* b_out  = (const float*)d_in[14];
  const float* W_read = (const float*)d_in[15];
  const float* b_read = (const float*)d_in[16];
  float* out = (float*)d_out;
  float* ws  = (float*)d_ws;

  k_gates_lstm<<<512, 256, 0, stream>>>(task, preads, h_prev, c_prev, W_ih, W_hh, b_lstm, ws);
  k_outproj_parse<<<134, 256, 0, stream>>>(W_out, b_out, ws);
  k_content<<<80, 1024, 0, stream>>>(memory, ws);
  k_write_path<<<16, 1024, 0, stream>>>(prw, pusage, pww, prec, ws, out);
  k_link<<<dim3(CHUNKS, BB), 512, 0, stream>>>(links, prw, memory, ws, out);
  k_readrw<<<128, 256, 0, stream>>>(memory, ws, out);
  k_final<<<16, 256, 0, stream>>>(W_read, b_read, ws, out);
}

// Round 7
// 202.304 us; speedup vs baseline: 1.2356x; 1.0349x over previous
//
#include <hip/hip_runtime.h>
#include <math.h>

// DNC single step, MI355X. All f32. B=16,N=2048,M=64,R=4,H=512.
constexpr int BB = 16, NN = 2048, MM = 64, RR = 4, HH = 512;
constexpr int CIN = 320, COUT = 535;
constexpr int CHUNKS = 64, ROWS = 32; // link kernel row-chunking (512 thr/block)

typedef float f32x4 __attribute__((ext_vector_type(4)));

// ---- output layout (floats): output, memory_new, link_new, p_new, usage, read_w
constexpr size_t O_OUT   = 0;
constexpr size_t O_MEM   = O_OUT + (size_t)BB * 64;
constexpr size_t O_LINK  = O_MEM + (size_t)BB * NN * MM;
constexpr size_t O_PNEW  = O_LINK + (size_t)BB * NN * NN;
constexpr size_t O_USAGE = O_PNEW + (size_t)BB * NN;
constexpr size_t O_READW = O_USAGE + (size_t)BB * NN;

// ---- workspace layout (floats)
constexpr size_t WS_H     = 0;                                   // B*512
constexpr size_t WS_OUTR  = WS_H + (size_t)BB * HH;              // B*535 (raw, for modes)
constexpr size_t WS_TASK  = WS_OUTR + (size_t)BB * COUT;         // B*64
constexpr size_t WS_RKEYS = WS_TASK + (size_t)BB * 64;           // B*256
constexpr size_t WS_RBETA = WS_RKEYS + (size_t)BB * 256;         // B*4
constexpr size_t WS_FGATE = WS_RBETA + (size_t)BB * 4;           // B*4
constexpr size_t WS_WKEY  = WS_FGATE + (size_t)BB * 4;           // B*64
constexpr size_t WS_WBETA = WS_WKEY + (size_t)BB * 64;           // B
constexpr size_t WS_ERASE = WS_WBETA + (size_t)BB;               // B*64
constexpr size_t WS_WVEC  = WS_ERASE + (size_t)BB * 64;          // B*64
constexpr size_t WS_AGATE = WS_WVEC + (size_t)BB * 64;           // B
constexpr size_t WS_WGATE = WS_AGATE + (size_t)BB;               // B
constexpr size_t WS_CONT  = WS_WGATE + (size_t)BB;               // B*5*N
constexpr size_t WS_WW    = WS_CONT + (size_t)BB * 5 * NN;       // B*N
constexpr size_t WS_FWD   = WS_WW + (size_t)BB * NN;             // B*4*N
constexpr size_t WS_BPART = WS_FWD + (size_t)BB * 4 * NN;        // B*CHUNKS*4*N
constexpr size_t WS_RPART = WS_BPART + (size_t)BB * CHUNKS * 4 * NN; // B*8*256
constexpr size_t WS_TOTAL = WS_RPART + (size_t)BB * 8 * 256;

__device__ __forceinline__ float sigf(float x) { return 1.0f / (1.0f + expf(-x)); }
__device__ __forceinline__ float oneplusf(float x) {
  return 1.0f + fmaxf(x, 0.0f) + log1pf(expf(-fabsf(x)));
}

// ---- K1: LSTM gates + cell fused. One block per hidden index j.
__global__ void k_gates_lstm(const float* __restrict__ task, const float* __restrict__ prev_reads,
                             const float* __restrict__ h_prev, const float* __restrict__ c_prev,
                             const float* __restrict__ W_ih, const float* __restrict__ W_hh,
                             const float* __restrict__ b_lstm, float* __restrict__ ws) {
  int tid = threadIdx.x, lane = tid & 63, wave = tid >> 6;
  int j = blockIdx.x;            // 0..511
  int row = wave * HH + j;       // gate row in [0,2048)
  __shared__ float gv[4][16];
  float acc[16];
#pragma unroll
  for (int b = 0; b < 16; b++) acc[b] = 0.f;
#pragma unroll
  for (int s = 0; s < 5; s++) {
    int k = s * 64 + lane;
    float wv = W_ih[(size_t)row * CIN + k];
    if (s == 0) {
#pragma unroll
      for (int b = 0; b < 16; b++) acc[b] += wv * task[b * 64 + k];
    } else {
#pragma unroll
      for (int b = 0; b < 16; b++) acc[b] += wv * prev_reads[b * 256 + (k - 64)];
    }
  }
#pragma unroll
  for (int s = 0; s < 8; s++) {
    int k = s * 64 + lane;
    float wv = W_hh[(size_t)row * HH + k];
#pragma unroll
    for (int b = 0; b < 16; b++) acc[b] += wv * h_prev[b * HH + k];
  }
#pragma unroll
  for (int b = 0; b < 16; b++) {
#pragma unroll
    for (int off = 32; off >= 1; off >>= 1) acc[b] += __shfl_xor(acc[b], off);
  }
  float val = 0.f;
#pragma unroll
  for (int b = 0; b < 16; b++) if (lane == b) val = acc[b];
  if (lane < 16) gv[wave][lane] = val + b_lstm[row];
  __syncthreads();
  if (tid < 16) {
    int b = tid;
    float gi = gv[0][b], gf = gv[1][b], gg = gv[2][b], go = gv[3][b];
    float c = sigf(gf) * c_prev[b * HH + j] + sigf(gi) * tanhf(gg);
    ws[WS_H + (size_t)b * HH + j] = sigf(go) * tanhf(c);
  }
}

// ---- K2: out_raw = h @ W_out^T + b_out, fused parse (one wave per row j<535)
__global__ void k_outproj_parse(const float* __restrict__ W_out, const float* __restrict__ b_out,
                                float* __restrict__ ws) {
  int tid = threadIdx.x, lane = tid & 63, wave = tid >> 6;
  int j = blockIdx.x * 4 + wave;
  if (j >= COUT) return;
  float acc[16];
#pragma unroll
  for (int b = 0; b < 16; b++) acc[b] = 0.f;
#pragma unroll
  for (int s = 0; s < 8; s++) {
    int k = s * 64 + lane;
    float wv = W_out[j * HH + k];
#pragma unroll
    for (int b = 0; b < 16; b++) acc[b] += wv * ws[WS_H + (size_t)b * HH + k];
  }
#pragma unroll
  for (int b = 0; b < 16; b++) {
#pragma unroll
    for (int off = 32; off >= 1; off >>= 1) acc[b] += __shfl_xor(acc[b], off);
  }
  float bias = b_out[j];
  float val = 0.f;
#pragma unroll
  for (int b = 0; b < 16; b++) if (lane == b) val = acc[b];
  if (lane < 16) {
    int b = lane;
    float v = val + bias;
    ws[WS_OUTR + (size_t)b * COUT + j] = v; // raw kept for read-mode softmax
    if (j < 64)       ws[WS_TASK + b * 64 + j] = sigf(v);
    else if (j < 320) ws[WS_RKEYS + b * 256 + (j - 64)] = sigf(v);
    else if (j < 324) ws[WS_RBETA + b * 4 + (j - 320)] = oneplusf(v);
    else if (j < 328) ws[WS_FGATE + b * 4 + (j - 324)] = sigf(v);
    else if (j < 392) ws[WS_WKEY + b * 64 + (j - 328)] = sigf(v);
    else if (j == 392) ws[WS_WBETA + b] = oneplusf(v);
    else if (j < 457) ws[WS_ERASE + b * 64 + (j - 393)] = sigf(v);
    else if (j < 521) ws[WS_WVEC + b * 64 + (j - 457)] = sigf(v);
    else if (j == 521) ws[WS_AGATE + b] = sigf(v);
    else if (j == 522) ws[WS_WGATE + b] = sigf(v);
  }
}

// ---- K3: content scores + softmax, one block per (b,key) (fused)
__global__ void __launch_bounds__(1024) k_content(const float* __restrict__ memory,
                                                  float* __restrict__ ws) {
  int bk = blockIdx.x; // b*5+k
  int b = bk / 5, k = bk % 5;
  int t = threadIdx.x, lane = t & 63, wave = t >> 6;
  __shared__ __align__(16) float kb[64];
  __shared__ float sc[NN];
  __shared__ float red[16];
  __shared__ float skn, sbeta;
  if (t < 64) kb[t] = (k < 4) ? ws[WS_RKEYS + b * 256 + k * 64 + t] : ws[WS_WKEY + b * 64 + t];
  if (t == 64) sbeta = (k < 4) ? ws[WS_RBETA + b * 4 + k] : ws[WS_WBETA + b];
  __syncthreads();
  if (wave == 0) {
    float kv = kb[lane];
    float ss = kv * kv;
#pragma unroll
    for (int off = 32; off >= 1; off >>= 1) ss += __shfl_xor(ss, off);
    if (lane == 0) skn = sqrtf(ss);
  }
  __syncthreads();
  float kn = skn, beta = sbeta;
  int r = lane >> 4, c = lane & 15;
  float4 key4 = *reinterpret_cast<const float4*>(&kb[c * 4]);
  for (int i = 0; i < 32; i++) {
    int n = wave * 128 + i * 4 + r;
    float4 v = *reinterpret_cast<const float4*>(&memory[((size_t)b * NN + n) * MM + c * 4]);
    float d = v.x * key4.x + v.y * key4.y + v.z * key4.z + v.w * key4.w;
    float s2 = v.x * v.x + v.y * v.y + v.z * v.z + v.w * v.w;
#pragma unroll
    for (int off = 1; off <= 8; off <<= 1) {
      d += __shfl_xor(d, off);
      s2 += __shfl_xor(s2, off);
    }
    if (c == 0) sc[n] = beta * d / (kn * sqrtf(s2) + 1e-8f);
  }
  __syncthreads();
  float v0 = sc[t], v1 = sc[t + 1024];
  float mx = fmaxf(v0, v1);
#pragma unroll
  for (int off = 32; off >= 1; off >>= 1) mx = fmaxf(mx, __shfl_xor(mx, off));
  if (lane == 0) red[wave] = mx;
  __syncthreads();
  mx = red[0];
  for (int w2 = 1; w2 < 16; w2++) mx = fmaxf(mx, red[w2]);
  float e0 = expf(v0 - mx), e1 = expf(v1 - mx);
  float s = e0 + e1;
#pragma unroll
  for (int off = 32; off >= 1; off >>= 1) s += __shfl_xor(s, off);
  __syncthreads();
  if (lane == 0) red[wave] = s;
  __syncthreads();
  s = 0.f;
  for (int w2 = 0; w2 < 16; w2++) s += red[w2];
  float inv = 1.f / s;
  float* dst = ws + WS_CONT + (size_t)bk * NN;
  dst[t] = e0 * inv;
  dst[t + 1024] = e1 * inv;
}

// ---- K4: usage + allocation + write weights + p_new, one block per b.
// Hybrid bitonic sort (registers/shuffles for j<=64, LDS for j>=128).
__global__ void __launch_bounds__(1024) k_write_path(
    const float* __restrict__ prw, const float* __restrict__ pu,
    const float* __restrict__ pww, const float* __restrict__ prec,
    float* __restrict__ ws, float* __restrict__ out) {
  int b = blockIdx.x, t = threadIdx.x, lane = t & 63, wave = t >> 6;
  __shared__ float sv[NN];
  __shared__ int si[NN];
  __shared__ float al[NN];
  __shared__ float wred[16];
  float fg[4];
#pragma unroll
  for (int r = 0; r < 4; r++) fg[r] = ws[WS_FGATE + b * 4 + r];
  float v0, v1; int i0_, i1_;
  {
    int n = 2 * t;
    float2 a2 = *reinterpret_cast<const float2*>(&pu[(size_t)b * NN + n]);
    float2 w2 = *reinterpret_cast<const float2*>(&pww[(size_t)b * NN + n]);
    float psi0 = 1.f, psi1 = 1.f;
#pragma unroll
    for (int r = 0; r < 4; r++) {
      float2 p2 = *reinterpret_cast<const float2*>(&prw[((size_t)b * 4 + r) * NN + n]);
      psi0 *= (1.f - fg[r] * p2.x);
      psi1 *= (1.f - fg[r] * p2.y);
    }
    v0 = (a2.x + w2.x - a2.x * w2.x) * psi0;
    v1 = (a2.y + w2.y - a2.y * w2.y) * psi1;
    float2 u2; u2.x = v0; u2.y = v1;
    *reinterpret_cast<float2*>(&out[O_USAGE + (size_t)b * NN + n]) = u2;
    i0_ = n; i1_ = n + 1;
  }

  auto cmp_in = [&](int k) {
    bool up = ((t & (k >> 1)) == 0);
    bool less10 = (v1 < v0) || (v1 == v0 && i1_ < i0_);
    if (up ? less10 : !less10) {
      float tv = v0; v0 = v1; v1 = tv;
      int ti = i0_; i0_ = i1_; i1_ = ti;
    }
  };
  auto shfl_stage = [&](int j, int k) {
    int m = j >> 1;
    float pv0 = __shfl_xor(v0, m), pv1 = __shfl_xor(v1, m);
    int pi0 = __shfl_xor(i0_, m), pi1 = __shfl_xor(i1_, m);
    bool lower = ((t & m) == 0);
    bool up = ((t & (k >> 1)) == 0);
    bool lessP0 = (pv0 < v0) || (pv0 == v0 && pi0 < i0_);
    if (up ? (lower ? lessP0 : !lessP0) : (lower ? !lessP0 : lessP0)) { v0 = pv0; i0_ = pi0; }
    bool lessP1 = (pv1 < v1) || (pv1 == v1 && pi1 < i1_);
    if (up ? (lower ? lessP1 : !lessP1) : (lower ? !lessP1 : lessP1)) { v1 = pv1; i1_ = pi1; }
  };
  auto lds_stages = [&](int k, int jhi) {
    sv[2 * t] = v0; si[2 * t] = i0_; sv[2 * t + 1] = v1; si[2 * t + 1] = i1_;
    __syncthreads();
    for (int j = jhi; j >= 128; j >>= 1) {
#pragma unroll
      for (int e = 0; e < 2; e++) {
        int idx = t + e * 1024;
        int l = idx ^ j;
        if (l > idx) {
          bool up = ((idx & k) == 0);
          float va = sv[idx], vb = sv[l];
          int ia = si[idx], ib = si[l];
          bool lessBA = (vb < va) || (vb == va && ib < ia);
          if (up ? lessBA : !lessBA) { sv[idx] = vb; sv[l] = va; si[idx] = ib; si[l] = ia; }
        }
      }
      __syncthreads();
    }
    v0 = sv[2 * t]; i0_ = si[2 * t]; v1 = sv[2 * t + 1]; i1_ = si[2 * t + 1];
  };

#pragma unroll
  for (int kk = 1; kk <= 7; kk++) {
    int k = 1 << kk;
#pragma unroll 6
    for (int j = k >> 1; j >= 2; j >>= 1) shfl_stage(j, k);
    cmp_in(k);
  }
  lds_stages(256, 128);
#pragma unroll 6
  for (int j = 64; j >= 2; j >>= 1) shfl_stage(j, 256);
  cmp_in(256);
  lds_stages(512, 256);
#pragma unroll 6
  for (int j = 64; j >= 2; j >>= 1) shfl_stage(j, 512);
  cmp_in(512);
  lds_stages(1024, 512);
#pragma unroll 6
  for (int j = 64; j >= 2; j >>= 1) shfl_stage(j, 1024);
  cmp_in(1024);
  lds_stages(2048, 1024);
#pragma unroll 6
  for (int j = 64; j >= 2; j >>= 1) shfl_stage(j, 2048);
  cmp_in(2048);

  float lp = v0 * v1;
  float x = lp;
#pragma unroll
  for (int off = 1; off < 64; off <<= 1) {
    float y = __shfl_up(x, off);
    if (lane >= off) x *= y;
  }
  if (lane == 63) wred[wave] = x;
  float ex = __shfl_up(x, 1);
  if (lane == 0) ex = 1.f;
  __syncthreads();
  float base = 1.f;
  for (int w2 = 0; w2 < wave; w2++) base *= wred[w2];
  float E = base * ex;
  al[i0_] = (1.f - v0) * E;
  E *= v0;
  al[i1_] = (1.f - v1) * E;
  __syncthreads();
  float ag = ws[WS_AGATE + b], wg = ws[WS_WGATE + b];
  float wwv[2], ssum = 0.f;
#pragma unroll
  for (int e = 0; e < 2; e++) {
    int n = t + e * 1024;
    float cw = ws[WS_CONT + ((size_t)b * 5 + 4) * NN + n];
    wwv[e] = wg * (ag * al[n] + (1.f - ag) * cw);
    ws[WS_WW + (size_t)b * NN + n] = wwv[e];
    ssum += wwv[e];
  }
#pragma unroll
  for (int off = 32; off >= 1; off >>= 1) ssum += __shfl_xor(ssum, off);
  __syncthreads();
  if (lane == 0) wred[wave] = ssum;
  __syncthreads();
  float tot = 0.f;
  for (int w2 = 0; w2 < 16; w2++) tot += wred[w2];
  float om = 1.f - tot;
#pragma unroll
  for (int e = 0; e < 2; e++) {
    int n = t + e * 1024;
    out[O_PNEW + (size_t)b * NN + n] = om * prec[(size_t)b * NN + n] + wwv[e];
  }
}

// ---- K5: fused streaming pass over L: fwd_w, bwd partials, link_new, memory_new.
// 512 threads (8 waves). Row-PAIR processing with distance-2 prefetch (named regs,
// rolled loop): 2-4 loads in flight per wave to cover ~900cy HBM latency.
__global__ void __launch_bounds__(512) k_link(const float* __restrict__ L,
                                              const float* __restrict__ wprev,
                                              const float* __restrict__ mem,
                                              float* __restrict__ ws, float* __restrict__ out) {
  int b = blockIdx.y, chunk = blockIdx.x;
  int i0 = chunk * ROWS;
  int tid = threadIdx.x, lane = tid & 63, wave = tid >> 6; // 8 waves
  __shared__ float wwrow[ROWS];
  __shared__ float wprow[4][ROWS];
  __shared__ float fpart[8][4][ROWS]; // 4 KB
  if (tid < ROWS) wwrow[tid] = ws[WS_WW + (size_t)b * NN + i0 + tid];
  if (tid >= 64 && tid < 64 + 4 * ROWS) {
    int r = (tid - 64) >> 5, ii = (tid - 64) & 31;
    wprow[r][ii] = wprev[((size_t)b * 4 + r) * NN + i0 + ii];
  }
  int j = tid * 4; // fixed 4 columns per thread
  f32x4 wp[4], pn, wwj;
#pragma unroll
  for (int r = 0; r < 4; r++)
    wp[r] = *reinterpret_cast<const f32x4*>(&wprev[((size_t)b * 4 + r) * NN + j]);
  pn = *reinterpret_cast<const f32x4*>(&out[O_PNEW + (size_t)b * NN + j]);
  wwj = *reinterpret_cast<const f32x4*>(&ws[WS_WW + (size_t)b * NN + j]);
  const float* Lb = L + (size_t)b * NN * NN;
  float* linkb = out + O_LINK + (size_t)b * NN * NN;
  const f32x4* Lrow = reinterpret_cast<const f32x4*>(Lb) + tid; // + i*512 per row
  // issue first pair before the barrier/memnew so they overlap
  f32x4 vA = __builtin_nontemporal_load(Lrow + (size_t)(i0 + 0) * 512);
  f32x4 vB = __builtin_nontemporal_load(Lrow + (size_t)(i0 + 1) * 512);
  __syncthreads();
  // fused memory_new for rows i0..i0+ROWS-1 (ROWS*64 = 2048 elems)
#pragma unroll
  for (int e = 0; e < 4; e++) {
    int idx = e * 512 + tid;
    int ii = idx >> 6, m = idx & 63;
    size_t g = ((size_t)b * NN + i0 + ii) * MM + m;
    float wwv = wwrow[ii];
    out[O_MEM + g] = mem[g] * (1.f - wwv * ws[WS_ERASE + b * 64 + m]) + wwv * ws[WS_WVEC + b * 64 + m];
  }
  f32x4 bacc[4];
#pragma unroll
  for (int r = 0; r < 4; r++) bacc[r] = (f32x4)(0.f);
  bool hi32 = (lane & 32) != 0;
  bool hi16 = (lane & 16) != 0;
  int g4 = lane >> 4;
  int rsel = ((g4 & 1) << 1) | (g4 >> 1); // {0,2,1,3}

  auto process = [&](int ii, f32x4 v) {
    int i = i0 + ii;
    float f0 = v[0] * wp[0][0] + v[1] * wp[0][1] + v[2] * wp[0][2] + v[3] * wp[0][3];
    float f1 = v[0] * wp[1][0] + v[1] * wp[1][1] + v[2] * wp[1][2] + v[3] * wp[1][3];
    float f2 = v[0] * wp[2][0] + v[1] * wp[2][1] + v[2] * wp[2][2] + v[3] * wp[2][3];
    float f3 = v[0] * wp[3][0] + v[1] * wp[3][1] + v[2] * wp[3][2] + v[3] * wp[3][3];
    // fold-tree: pack 4 dots into lane quadrants, then shared reduce
    float u01 = (hi32 ? f1 : f0) + __shfl_xor(hi32 ? f0 : f1, 32);
    float u23 = (hi32 ? f3 : f2) + __shfl_xor(hi32 ? f2 : f3, 32);
    float w = (hi16 ? u23 : u01) + __shfl_xor(hi16 ? u01 : u23, 16);
    w += __shfl_xor(w, 8);
    w += __shfl_xor(w, 4);
    w += __shfl_xor(w, 2);
    w += __shfl_xor(w, 1);
    if ((lane & 15) == 0) fpart[wave][rsel][ii] = w;
#pragma unroll
    for (int r = 0; r < 4; r++) {
      float wr = wprow[r][ii];
      bacc[r][0] += wr * v[0]; bacc[r][1] += wr * v[1];
      bacc[r][2] += wr * v[2]; bacc[r][3] += wr * v[3];
    }
    float wwi = wwrow[ii];
    f32x4 o;
    o[0] = (1.f - wwi - wwj[0]) * v[0] + wwi * pn[0];
    o[1] = (1.f - wwi - wwj[1]) * v[1] + wwi * pn[1];
    o[2] = (1.f - wwi - wwj[2]) * v[2] + wwi * pn[2];
    o[3] = (1.f - wwi - wwj[3]) * v[3] + wwi * pn[3];
    unsigned di = (unsigned)(i - j);
    if (di < 4u) {
      if (di == 0) o[0] = 0.f;
      else if (di == 1) o[1] = 0.f;
      else if (di == 2) o[2] = 0.f;
      else o[3] = 0.f;
    }
    __builtin_nontemporal_store(o, reinterpret_cast<f32x4*>(linkb + (size_t)i * NN) + tid);
  };

  for (int ii = 0; ii < ROWS; ii += 2) {
    f32x4 pA = vA, pB = vB;
    if (ii + 2 < ROWS) {
      pA = __builtin_nontemporal_load(Lrow + (size_t)(i0 + ii + 2) * 512);
      pB = __builtin_nontemporal_load(Lrow + (size_t)(i0 + ii + 3) * 512);
    }
    process(ii, vA);
    process(ii + 1, vB);
    vA = pA; vB = pB;
  }
  __syncthreads();
  if (tid < 4 * ROWS) {
    int r = tid >> 5, ii = tid & 31;
    float s = 0.f;
#pragma unroll
    for (int w2 = 0; w2 < 8; w2++) s += fpart[w2][r][ii];
    ws[WS_FWD + ((size_t)b * 4 + r) * NN + i0 + ii] = s;
  }
#pragma unroll
  for (int r = 0; r < 4; r++)
    *reinterpret_cast<f32x4*>(
        &ws[WS_BPART + (((size_t)b * CHUNKS + chunk) * 4 + r) * NN + j]) = bacc[r];
}

// ---- K6: bwd chunk-reduce + read modes + read_w + read partial dots (fused)
__global__ void __launch_bounds__(256) k_readrw(const float* __restrict__ memory,
                                                float* __restrict__ ws, float* __restrict__ out) {
  int b = blockIdx.x >> 3, chunk = blockIdx.x & 7;
  int n0 = chunk * 256;
  int t = threadIdx.x, lane = t & 63, wave = t >> 6;
  __shared__ float fm[4][3];
  __shared__ float rwl[4][256];
  __shared__ float part[4][4][64];
  if (t < 4) {
    const float* o = ws + WS_OUTR + (size_t)b * COUT + 523 + t * 3;
    float a = o[0], bb = o[1], cc = o[2];
    float m = fmaxf(a, fmaxf(bb, cc));
    float ea = expf(a - m), eb = expf(bb - m), ec = expf(cc - m);
    float iv = 1.f / (ea + eb + ec);
    fm[t][0] = ea * iv; fm[t][1] = eb * iv; fm[t][2] = ec * iv;
  }
  __syncthreads();
#pragma unroll
  for (int r = 0; r < 4; r++) {
    int n = n0 + t;
    float bwd = 0.f;
    for (int c2 = 0; c2 < CHUNKS; c2++)
      bwd += ws[WS_BPART + (((size_t)b * CHUNKS + c2) * 4 + r) * NN + n];
    float fwd = ws[WS_FWD + ((size_t)b * 4 + r) * NN + n];
    float cont = ws[WS_CONT + ((size_t)b * 5 + r) * NN + n];
    float rw = fm[r][0] * bwd + fm[r][1] * cont + fm[r][2] * fwd;
    out[O_READW + ((size_t)b * 4 + r) * NN + n] = rw;
    rwl[r][t] = rw;
  }
  __syncthreads();
  float acc[4] = {0.f, 0.f, 0.f, 0.f};
  for (int ii = 0; ii < 64; ii++) {
    int nl = wave * 64 + ii;
    float mv = memory[((size_t)b * NN + n0 + nl) * MM + lane];
#pragma unroll
    for (int r = 0; r < 4; r++) acc[r] += rwl[r][nl] * mv;
  }
#pragma unroll
  for (int r = 0; r < 4; r++) part[wave][r][lane] = acc[r];
  __syncthreads();
  { int r = t >> 6, m = t & 63;
    float s = part[0][r][m] + part[1][r][m] + part[2][r][m] + part[3][r][m];
    ws[WS_RPART + ((size_t)(b * 8 + chunk)) * 256 + t] = s; }
}

// ---- K7: reduce read partials + read projection + final output
__global__ void k_final(const float* __restrict__ W_read, const float* __restrict__ b_read,
                        const float* __restrict__ ws, float* __restrict__ out) {
  int b = blockIdx.x, t = threadIdx.x, lane = t & 63, wave = t >> 6;
  __shared__ float rds[256];
  float s = 0.f;
  for (int c = 0; c < 8; c++) s += ws[WS_RPART + ((size_t)(b * 8 + c)) * 256 + t];
  rds[t] = s;
  __syncthreads();
  for (int oi = 0; oi < 16; oi++) {
    int o = wave * 16 + oi;
    float acc = 0.f;
#pragma unroll
    for (int s2 = 0; s2 < 4; s2++) {
      int kk = s2 * 64 + lane;
      acc += W_read[o * 256 + kk] * rds[kk];
    }
#pragma unroll
    for (int off = 32; off >= 1; off >>= 1) acc += __shfl_xor(acc, off);
    if (lane == 0) {
      float ro = sigf(acc + b_read[o]);
      out[O_OUT + b * 64 + o] = sigf(ro + ws[WS_TASK + b * 64 + o]);
    }
  }
}

extern "C" void kernel_launch(void* const* d_in, const int* in_sizes, int n_in,
                              void* d_out, int out_size, void* d_ws, size_t ws_size,
                              hipStream_t stream) {
  (void)in_sizes; (void)n_in; (void)out_size; (void)ws_size;
  const float* task   = (const float*)d_in[0];
  const float* memory = (const float*)d_in[1];
  const float* links  = (const float*)d_in[2];
  const float* preads = (const float*)d_in[3];
  const float* prw    = (const float*)d_in[4];
  const float* pusage = (const float*)d_in[5];
  const float* pww    = (const float*)d_in[6];
  const float* prec   = (const float*)d_in[7];
  const float* h_prev = (const float*)d_in[8];
  const float* c_prev = (const float*)d_in[9];
  const float* W_ih   = (const float*)d_in[10];
  const float* W_hh   = (const float*)d_in[11];
  const float* b_lstm = (const float*)d_in[12];
  const float* W_out  = (const float*)d_in[13];
  const float* b_out  = (const float*)d_in[14];
  const float* W_read = (const float*)d_in[15];
  const float* b_read = (const float*)d_in[16];
  float* out = (float*)d_out;
  float* ws  = (float*)d_ws;

  k_gates_lstm<<<512, 256, 0, stream>>>(task, preads, h_prev, c_prev, W_ih, W_hh, b_lstm, ws);
  k_outproj_parse<<<134, 256, 0, stream>>>(W_out, b_out, ws);
  k_content<<<80, 1024, 0, stream>>>(memory, ws);
  k_write_path<<<16, 1024, 0, stream>>>(prw, pusage, pww, prec, ws, out);
  k_link<<<dim3(CHUNKS, BB), 512, 0, stream>>>(links, prw, memory, ws, out);
  k_readrw<<<128, 256, 0, stream>>>(memory, ws, out);
  k_final<<<16, 256, 0, stream>>>(W_read, b_read, ws, out);
}

// Round 8
// 201.249 us; speedup vs baseline: 1.2421x; 1.0052x over previous
//
#include <hip/hip_runtime.h>
#include <math.h>

// DNC single step, MI355X. All f32. B=16,N=2048,M=64,R=4,H=512.
constexpr int BB = 16, NN = 2048, MM = 64, RR = 4, HH = 512;
constexpr int CIN = 320, COUT = 535;
constexpr int CHUNKS = 64, ROWS = 32; // link kernel row-chunking (512 thr/block)
constexpr int FPS = 132;              // fpart row stride (floats), 4-aligned, %32=4

typedef float f32x4 __attribute__((ext_vector_type(4)));

// ---- output layout (floats): output, memory_new, link_new, p_new, usage, read_w
constexpr size_t O_OUT   = 0;
constexpr size_t O_MEM   = O_OUT + (size_t)BB * 64;
constexpr size_t O_LINK  = O_MEM + (size_t)BB * NN * MM;
constexpr size_t O_PNEW  = O_LINK + (size_t)BB * NN * NN;
constexpr size_t O_USAGE = O_PNEW + (size_t)BB * NN;
constexpr size_t O_READW = O_USAGE + (size_t)BB * NN;

// ---- workspace layout (floats)
constexpr size_t WS_H     = 0;                                   // B*512
constexpr size_t WS_OUTR  = WS_H + (size_t)BB * HH;              // B*535 (raw, for modes)
constexpr size_t WS_TASK  = WS_OUTR + (size_t)BB * COUT;         // B*64
constexpr size_t WS_RKEYS = WS_TASK + (size_t)BB * 64;           // B*256
constexpr size_t WS_RBETA = WS_RKEYS + (size_t)BB * 256;         // B*4
constexpr size_t WS_FGATE = WS_RBETA + (size_t)BB * 4;           // B*4
constexpr size_t WS_WKEY  = WS_FGATE + (size_t)BB * 4;           // B*64
constexpr size_t WS_WBETA = WS_WKEY + (size_t)BB * 64;           // B
constexpr size_t WS_ERASE = WS_WBETA + (size_t)BB;               // B*64
constexpr size_t WS_WVEC  = WS_ERASE + (size_t)BB * 64;          // B*64
constexpr size_t WS_AGATE = WS_WVEC + (size_t)BB * 64;           // B
constexpr size_t WS_WGATE = WS_AGATE + (size_t)BB;               // B
constexpr size_t WS_CONT  = WS_WGATE + (size_t)BB;               // B*5*N
constexpr size_t WS_WW    = WS_CONT + (size_t)BB * 5 * NN;       // B*N
constexpr size_t WS_FWD   = WS_WW + (size_t)BB * NN;             // B*4*N
constexpr size_t WS_BPART = WS_FWD + (size_t)BB * 4 * NN;        // B*CHUNKS*4*N
constexpr size_t WS_RPART = WS_BPART + (size_t)BB * CHUNKS * 4 * NN; // B*8*256
constexpr size_t WS_TOTAL = WS_RPART + (size_t)BB * 8 * 256;

__device__ __forceinline__ float sigf(float x) { return 1.0f / (1.0f + expf(-x)); }
__device__ __forceinline__ float oneplusf(float x) {
  return 1.0f + fmaxf(x, 0.0f) + log1pf(expf(-fabsf(x)));
}

// ---- K1: LSTM gates + cell fused. One block per hidden index j.
__global__ void k_gates_lstm(const float* __restrict__ task, const float* __restrict__ prev_reads,
                             const float* __restrict__ h_prev, const float* __restrict__ c_prev,
                             const float* __restrict__ W_ih, const float* __restrict__ W_hh,
                             const float* __restrict__ b_lstm, float* __restrict__ ws) {
  int tid = threadIdx.x, lane = tid & 63, wave = tid >> 6;
  int j = blockIdx.x;            // 0..511
  int row = wave * HH + j;       // gate row in [0,2048)
  __shared__ float gv[4][16];
  float acc[16];
#pragma unroll
  for (int b = 0; b < 16; b++) acc[b] = 0.f;
#pragma unroll
  for (int s = 0; s < 5; s++) {
    int k = s * 64 + lane;
    float wv = W_ih[(size_t)row * CIN + k];
    if (s == 0) {
#pragma unroll
      for (int b = 0; b < 16; b++) acc[b] += wv * task[b * 64 + k];
    } else {
#pragma unroll
      for (int b = 0; b < 16; b++) acc[b] += wv * prev_reads[b * 256 + (k - 64)];
    }
  }
#pragma unroll
  for (int s = 0; s < 8; s++) {
    int k = s * 64 + lane;
    float wv = W_hh[(size_t)row * HH + k];
#pragma unroll
    for (int b = 0; b < 16; b++) acc[b] += wv * h_prev[b * HH + k];
  }
#pragma unroll
  for (int b = 0; b < 16; b++) {
#pragma unroll
    for (int off = 32; off >= 1; off >>= 1) acc[b] += __shfl_xor(acc[b], off);
  }
  float val = 0.f;
#pragma unroll
  for (int b = 0; b < 16; b++) if (lane == b) val = acc[b];
  if (lane < 16) gv[wave][lane] = val + b_lstm[row];
  __syncthreads();
  if (tid < 16) {
    int b = tid;
    float gi = gv[0][b], gf = gv[1][b], gg = gv[2][b], go = gv[3][b];
    float c = sigf(gf) * c_prev[b * HH + j] + sigf(gi) * tanhf(gg);
    ws[WS_H + (size_t)b * HH + j] = sigf(go) * tanhf(c);
  }
}

// ---- K2: out_raw = h @ W_out^T + b_out, fused parse (one wave per row j<535)
__global__ void k_outproj_parse(const float* __restrict__ W_out, const float* __restrict__ b_out,
                                float* __restrict__ ws) {
  int tid = threadIdx.x, lane = tid & 63, wave = tid >> 6;
  int j = blockIdx.x * 4 + wave;
  if (j >= COUT) return;
  float acc[16];
#pragma unroll
  for (int b = 0; b < 16; b++) acc[b] = 0.f;
#pragma unroll
  for (int s = 0; s < 8; s++) {
    int k = s * 64 + lane;
    float wv = W_out[j * HH + k];
#pragma unroll
    for (int b = 0; b < 16; b++) acc[b] += wv * ws[WS_H + (size_t)b * HH + k];
  }
#pragma unroll
  for (int b = 0; b < 16; b++) {
#pragma unroll
    for (int off = 32; off >= 1; off >>= 1) acc[b] += __shfl_xor(acc[b], off);
  }
  float bias = b_out[j];
  float val = 0.f;
#pragma unroll
  for (int b = 0; b < 16; b++) if (lane == b) val = acc[b];
  if (lane < 16) {
    int b = lane;
    float v = val + bias;
    ws[WS_OUTR + (size_t)b * COUT + j] = v; // raw kept for read-mode softmax
    if (j < 64)       ws[WS_TASK + b * 64 + j] = sigf(v);
    else if (j < 320) ws[WS_RKEYS + b * 256 + (j - 64)] = sigf(v);
    else if (j < 324) ws[WS_RBETA + b * 4 + (j - 320)] = oneplusf(v);
    else if (j < 328) ws[WS_FGATE + b * 4 + (j - 324)] = sigf(v);
    else if (j < 392) ws[WS_WKEY + b * 64 + (j - 328)] = sigf(v);
    else if (j == 392) ws[WS_WBETA + b] = oneplusf(v);
    else if (j < 457) ws[WS_ERASE + b * 64 + (j - 393)] = sigf(v);
    else if (j < 521) ws[WS_WVEC + b * 64 + (j - 457)] = sigf(v);
    else if (j == 521) ws[WS_AGATE + b] = sigf(v);
    else if (j == 522) ws[WS_WGATE + b] = sigf(v);
  }
}

// ---- K3: content scores + softmax, one block per (b,key) (fused)
__global__ void __launch_bounds__(1024) k_content(const float* __restrict__ memory,
                                                  float* __restrict__ ws) {
  int bk = blockIdx.x; // b*5+k
  int b = bk / 5, k = bk % 5;
  int t = threadIdx.x, lane = t & 63, wave = t >> 6;
  __shared__ __align__(16) float kb[64];
  __shared__ float sc[NN];
  __shared__ float red[16];
  __shared__ float skn, sbeta;
  if (t < 64) kb[t] = (k < 4) ? ws[WS_RKEYS + b * 256 + k * 64 + t] : ws[WS_WKEY + b * 64 + t];
  if (t == 64) sbeta = (k < 4) ? ws[WS_RBETA + b * 4 + k] : ws[WS_WBETA + b];
  __syncthreads();
  if (wave == 0) {
    float kv = kb[lane];
    float ss = kv * kv;
#pragma unroll
    for (int off = 32; off >= 1; off >>= 1) ss += __shfl_xor(ss, off);
    if (lane == 0) skn = sqrtf(ss);
  }
  __syncthreads();
  float kn = skn, beta = sbeta;
  int r = lane >> 4, c = lane & 15;
  float4 key4 = *reinterpret_cast<const float4*>(&kb[c * 4]);
  for (int i = 0; i < 32; i++) {
    int n = wave * 128 + i * 4 + r;
    float4 v = *reinterpret_cast<const float4*>(&memory[((size_t)b * NN + n) * MM + c * 4]);
    float d = v.x * key4.x + v.y * key4.y + v.z * key4.z + v.w * key4.w;
    float s2 = v.x * v.x + v.y * v.y + v.z * v.z + v.w * v.w;
#pragma unroll
    for (int off = 1; off <= 8; off <<= 1) {
      d += __shfl_xor(d, off);
      s2 += __shfl_xor(s2, off);
    }
    if (c == 0) sc[n] = beta * d / (kn * sqrtf(s2) + 1e-8f);
  }
  __syncthreads();
  float v0 = sc[t], v1 = sc[t + 1024];
  float mx = fmaxf(v0, v1);
#pragma unroll
  for (int off = 32; off >= 1; off >>= 1) mx = fmaxf(mx, __shfl_xor(mx, off));
  if (lane == 0) red[wave] = mx;
  __syncthreads();
  mx = red[0];
  for (int w2 = 1; w2 < 16; w2++) mx = fmaxf(mx, red[w2]);
  float e0 = expf(v0 - mx), e1 = expf(v1 - mx);
  float s = e0 + e1;
#pragma unroll
  for (int off = 32; off >= 1; off >>= 1) s += __shfl_xor(s, off);
  __syncthreads();
  if (lane == 0) red[wave] = s;
  __syncthreads();
  s = 0.f;
  for (int w2 = 0; w2 < 16; w2++) s += red[w2];
  float inv = 1.f / s;
  float* dst = ws + WS_CONT + (size_t)bk * NN;
  dst[t] = e0 * inv;
  dst[t + 1024] = e1 * inv;
}

// ---- K4: usage + allocation + write weights + p_new, one block per b.
// Hybrid bitonic sort (registers/shuffles for j<=64, LDS for j>=128).
__global__ void __launch_bounds__(1024) k_write_path(
    const float* __restrict__ prw, const float* __restrict__ pu,
    const float* __restrict__ pww, const float* __restrict__ prec,
    float* __restrict__ ws, float* __restrict__ out) {
  int b = blockIdx.x, t = threadIdx.x, lane = t & 63, wave = t >> 6;
  __shared__ float sv[NN];
  __shared__ int si[NN];
  __shared__ float al[NN];
  __shared__ float wred[16];
  float fg[4];
#pragma unroll
  for (int r = 0; r < 4; r++) fg[r] = ws[WS_FGATE + b * 4 + r];
  float v0, v1; int i0_, i1_;
  {
    int n = 2 * t;
    float2 a2 = *reinterpret_cast<const float2*>(&pu[(size_t)b * NN + n]);
    float2 w2 = *reinterpret_cast<const float2*>(&pww[(size_t)b * NN + n]);
    float psi0 = 1.f, psi1 = 1.f;
#pragma unroll
    for (int r = 0; r < 4; r++) {
      float2 p2 = *reinterpret_cast<const float2*>(&prw[((size_t)b * 4 + r) * NN + n]);
      psi0 *= (1.f - fg[r] * p2.x);
      psi1 *= (1.f - fg[r] * p2.y);
    }
    v0 = (a2.x + w2.x - a2.x * w2.x) * psi0;
    v1 = (a2.y + w2.y - a2.y * w2.y) * psi1;
    float2 u2; u2.x = v0; u2.y = v1;
    *reinterpret_cast<float2*>(&out[O_USAGE + (size_t)b * NN + n]) = u2;
    i0_ = n; i1_ = n + 1;
  }

  auto cmp_in = [&](int k) {
    bool up = ((t & (k >> 1)) == 0);
    bool less10 = (v1 < v0) || (v1 == v0 && i1_ < i0_);
    if (up ? less10 : !less10) {
      float tv = v0; v0 = v1; v1 = tv;
      int ti = i0_; i0_ = i1_; i1_ = ti;
    }
  };
  auto shfl_stage = [&](int j, int k) {
    int m = j >> 1;
    float pv0 = __shfl_xor(v0, m), pv1 = __shfl_xor(v1, m);
    int pi0 = __shfl_xor(i0_, m), pi1 = __shfl_xor(i1_, m);
    bool lower = ((t & m) == 0);
    bool up = ((t & (k >> 1)) == 0);
    bool lessP0 = (pv0 < v0) || (pv0 == v0 && pi0 < i0_);
    if (up ? (lower ? lessP0 : !lessP0) : (lower ? !lessP0 : lessP0)) { v0 = pv0; i0_ = pi0; }
    bool lessP1 = (pv1 < v1) || (pv1 == v1 && pi1 < i1_);
    if (up ? (lower ? lessP1 : !lessP1) : (lower ? !lessP1 : lessP1)) { v1 = pv1; i1_ = pi1; }
  };
  auto lds_stages = [&](int k, int jhi) {
    sv[2 * t] = v0; si[2 * t] = i0_; sv[2 * t + 1] = v1; si[2 * t + 1] = i1_;
    __syncthreads();
    for (int j = jhi; j >= 128; j >>= 1) {
#pragma unroll
      for (int e = 0; e < 2; e++) {
        int idx = t + e * 1024;
        int l = idx ^ j;
        if (l > idx) {
          bool up = ((idx & k) == 0);
          float va = sv[idx], vb = sv[l];
          int ia = si[idx], ib = si[l];
          bool lessBA = (vb < va) || (vb == va && ib < ia);
          if (up ? lessBA : !lessBA) { sv[idx] = vb; sv[l] = va; si[idx] = ib; si[l] = ia; }
        }
      }
      __syncthreads();
    }
    v0 = sv[2 * t]; i0_ = si[2 * t]; v1 = sv[2 * t + 1]; i1_ = si[2 * t + 1];
  };

#pragma unroll
  for (int kk = 1; kk <= 7; kk++) {
    int k = 1 << kk;
#pragma unroll 6
    for (int j = k >> 1; j >= 2; j >>= 1) shfl_stage(j, k);
    cmp_in(k);
  }
  lds_stages(256, 128);
#pragma unroll 6
  for (int j = 64; j >= 2; j >>= 1) shfl_stage(j, 256);
  cmp_in(256);
  lds_stages(512, 256);
#pragma unroll 6
  for (int j = 64; j >= 2; j >>= 1) shfl_stage(j, 512);
  cmp_in(512);
  lds_stages(1024, 512);
#pragma unroll 6
  for (int j = 64; j >= 2; j >>= 1) shfl_stage(j, 1024);
  cmp_in(1024);
  lds_stages(2048, 1024);
#pragma unroll 6
  for (int j = 64; j >= 2; j >>= 1) shfl_stage(j, 2048);
  cmp_in(2048);

  float lp = v0 * v1;
  float x = lp;
#pragma unroll
  for (int off = 1; off < 64; off <<= 1) {
    float y = __shfl_up(x, off);
    if (lane >= off) x *= y;
  }
  if (lane == 63) wred[wave] = x;
  float ex = __shfl_up(x, 1);
  if (lane == 0) ex = 1.f;
  __syncthreads();
  float base = 1.f;
  for (int w2 = 0; w2 < wave; w2++) base *= wred[w2];
  float E = base * ex;
  al[i0_] = (1.f - v0) * E;
  E *= v0;
  al[i1_] = (1.f - v1) * E;
  __syncthreads();
  float ag = ws[WS_AGATE + b], wg = ws[WS_WGATE + b];
  float wwv[2], ssum = 0.f;
#pragma unroll
  for (int e = 0; e < 2; e++) {
    int n = t + e * 1024;
    float cw = ws[WS_CONT + ((size_t)b * 5 + 4) * NN + n];
    wwv[e] = wg * (ag * al[n] + (1.f - ag) * cw);
    ws[WS_WW + (size_t)b * NN + n] = wwv[e];
    ssum += wwv[e];
  }
#pragma unroll
  for (int off = 32; off >= 1; off >>= 1) ssum += __shfl_xor(ssum, off);
  __syncthreads();
  if (lane == 0) wred[wave] = ssum;
  __syncthreads();
  float tot = 0.f;
  for (int w2 = 0; w2 < 16; w2++) tot += wred[w2];
  float om = 1.f - tot;
#pragma unroll
  for (int e = 0; e < 2; e++) {
    int n = t + e * 1024;
    out[O_PNEW + (size_t)b * NN + n] = om * prec[(size_t)b * NN + n] + wwv[e];
  }
}

// ---- K5: fused streaming pass over L: fwd_w, bwd partials, link_new, memory_new.
// 512 threads (8 waves). Store-first row body; 16-lane xor-reduce + fire-and-forget
// ds_write_b128 for fwd partials (no deep cross-lane chain on the critical path);
// 4-row named prefetch ring; one cooperative end-reduction.
__global__ void __launch_bounds__(512) k_link(const float* __restrict__ L,
                                              const float* __restrict__ wprev,
                                              const float* __restrict__ mem,
                                              float* __restrict__ ws, float* __restrict__ out) {
  int b = blockIdx.y, chunk = blockIdx.x;
  int i0 = chunk * ROWS;
  int tid = threadIdx.x, lane = tid & 63, wave = tid >> 6; // 8 waves
  __shared__ float wwrow[ROWS];
  __shared__ float wprow[4][ROWS];
  __shared__ __align__(16) float fpart[ROWS * FPS]; // 16.5 KB, stride-132 padded
  if (tid < ROWS) wwrow[tid] = ws[WS_WW + (size_t)b * NN + i0 + tid];
  if (tid >= 64 && tid < 64 + 4 * ROWS) {
    int r = (tid - 64) >> 5, ii = (tid - 64) & 31;
    wprow[r][ii] = wprev[((size_t)b * 4 + r) * NN + i0 + ii];
  }
  int j = tid * 4; // fixed 4 columns per thread
  f32x4 wp[4], pn, wwj;
#pragma unroll
  for (int r = 0; r < 4; r++)
    wp[r] = *reinterpret_cast<const f32x4*>(&wprev[((size_t)b * 4 + r) * NN + j]);
  pn = *reinterpret_cast<const f32x4*>(&out[O_PNEW + (size_t)b * NN + j]);
  wwj = *reinterpret_cast<const f32x4*>(&ws[WS_WW + (size_t)b * NN + j]);
  const float* Lb = L + (size_t)b * NN * NN;
  float* linkb = out + O_LINK + (size_t)b * NN * NN;
  const f32x4* Lrow = reinterpret_cast<const f32x4*>(Lb) + tid; // + i*512 per row
  // 4-row prefetch ring issued before the barrier/memnew so they overlap
  f32x4 vA = __builtin_nontemporal_load(Lrow + (size_t)(i0 + 0) * 512);
  f32x4 vB = __builtin_nontemporal_load(Lrow + (size_t)(i0 + 1) * 512);
  f32x4 vC = __builtin_nontemporal_load(Lrow + (size_t)(i0 + 2) * 512);
  f32x4 vD = __builtin_nontemporal_load(Lrow + (size_t)(i0 + 3) * 512);
  __syncthreads();
  // fused memory_new for rows i0..i0+ROWS-1 (ROWS*64 = 2048 elems)
#pragma unroll
  for (int e = 0; e < 4; e++) {
    int idx = e * 512 + tid;
    int ii = idx >> 6, m = idx & 63;
    size_t g = ((size_t)b * NN + i0 + ii) * MM + m;
    float wwv = wwrow[ii];
    out[O_MEM + g] = mem[g] * (1.f - wwv * ws[WS_ERASE + b * 64 + m]) + wwv * ws[WS_WVEC + b * 64 + m];
  }
  f32x4 bacc[4];
#pragma unroll
  for (int r = 0; r < 4; r++) bacc[r] = (f32x4)(0.f);
  int fpbase = (wave * 4 + (lane >> 4)) * 4; // this lane-group's slot in a row
  bool writer = (lane & 15) == 0;

  auto process = [&](int ii, f32x4 v) {
    int i = i0 + ii;
    // 1) link row out — depends only on v + broadcast scalars; store first
    float wwi = wwrow[ii];
    f32x4 o;
    o[0] = (1.f - wwi - wwj[0]) * v[0] + wwi * pn[0];
    o[1] = (1.f - wwi - wwj[1]) * v[1] + wwi * pn[1];
    o[2] = (1.f - wwi - wwj[2]) * v[2] + wwi * pn[2];
    o[3] = (1.f - wwi - wwj[3]) * v[3] + wwi * pn[3];
    unsigned di = (unsigned)(i - j);
    if (di < 4u) {
      if (di == 0) o[0] = 0.f;
      else if (di == 1) o[1] = 0.f;
      else if (di == 2) o[2] = 0.f;
      else o[3] = 0.f;
    }
    __builtin_nontemporal_store(o, reinterpret_cast<f32x4*>(linkb + (size_t)i * NN) + tid);
    // 2) fwd partial dots + 16-lane xor reduce (short independent chains)
    float f0 = v[0] * wp[0][0] + v[1] * wp[0][1] + v[2] * wp[0][2] + v[3] * wp[0][3];
    float f1 = v[0] * wp[1][0] + v[1] * wp[1][1] + v[2] * wp[1][2] + v[3] * wp[1][3];
    float f2 = v[0] * wp[2][0] + v[1] * wp[2][1] + v[2] * wp[2][2] + v[3] * wp[2][3];
    float f3 = v[0] * wp[3][0] + v[1] * wp[3][1] + v[2] * wp[3][2] + v[3] * wp[3][3];
#pragma unroll
    for (int off = 1; off <= 8; off <<= 1) {
      f0 += __shfl_xor(f0, off);
      f1 += __shfl_xor(f1, off);
      f2 += __shfl_xor(f2, off);
      f3 += __shfl_xor(f3, off);
    }
    if (writer) {
      f32x4 q; q[0] = f0; q[1] = f1; q[2] = f2; q[3] = f3;
      *reinterpret_cast<f32x4*>(&fpart[ii * FPS + fpbase]) = q;
    }
    // 3) bwd: column accumulation
#pragma unroll
    for (int r = 0; r < 4; r++) {
      float wr = wprow[r][ii];
      bacc[r][0] += wr * v[0]; bacc[r][1] += wr * v[1];
      bacc[r][2] += wr * v[2]; bacc[r][3] += wr * v[3];
    }
  };

  for (int ii = 0; ii < ROWS; ii += 2) {
    f32x4 pE = vC, pF = vD;
    if (ii + 4 < ROWS) {
      pE = __builtin_nontemporal_load(Lrow + (size_t)(i0 + ii + 4) * 512);
      pF = __builtin_nontemporal_load(Lrow + (size_t)(i0 + ii + 5) * 512);
    }
    process(ii, vA);
    process(ii + 1, vB);
    vA = vC; vB = vD;
    vC = pE; vD = pF;
  }
  // BPART before the barrier (doesn't touch fpart)
#pragma unroll
  for (int r = 0; r < 4; r++)
    *reinterpret_cast<f32x4*>(
        &ws[WS_BPART + (((size_t)b * CHUNKS + chunk) * 4 + r) * NN + j]) = bacc[r];
  __syncthreads();
  if (tid < 4 * ROWS) {
    int r = tid >> 5, i = tid & 31;
    float s = 0.f;
    for (int wg = 0; wg < 32; wg++) s += fpart[i * FPS + wg * 4 + r];
    ws[WS_FWD + ((size_t)b * 4 + r) * NN + i0 + i] = s;
  }
}

// ---- K6: bwd chunk-reduce + read modes + read_w + read partial dots (fused)
__global__ void __launch_bounds__(256) k_readrw(const float* __restrict__ memory,
                                                float* __restrict__ ws, float* __restrict__ out) {
  int b = blockIdx.x >> 3, chunk = blockIdx.x & 7;
  int n0 = chunk * 256;
  int t = threadIdx.x, lane = t & 63, wave = t >> 6;
  __shared__ float fm[4][3];
  __shared__ float rwl[4][256];
  __shared__ float part[4][4][64];
  if (t < 4) {
    const float* o = ws + WS_OUTR + (size_t)b * COUT + 523 + t * 3;
    float a = o[0], bb = o[1], cc = o[2];
    float m = fmaxf(a, fmaxf(bb, cc));
    float ea = expf(a - m), eb = expf(bb - m), ec = expf(cc - m);
    float iv = 1.f / (ea + eb + ec);
    fm[t][0] = ea * iv; fm[t][1] = eb * iv; fm[t][2] = ec * iv;
  }
  __syncthreads();
#pragma unroll
  for (int r = 0; r < 4; r++) {
    int n = n0 + t;
    float bwd = 0.f;
    for (int c2 = 0; c2 < CHUNKS; c2++)
      bwd += ws[WS_BPART + (((size_t)b * CHUNKS + c2) * 4 + r) * NN + n];
    float fwd = ws[WS_FWD + ((size_t)b * 4 + r) * NN + n];
    float cont = ws[WS_CONT + ((size_t)b * 5 + r) * NN + n];
    float rw = fm[r][0] * bwd + fm[r][1] * cont + fm[r][2] * fwd;
    out[O_READW + ((size_t)b * 4 + r) * NN + n] = rw;
    rwl[r][t] = rw;
  }
  __syncthreads();
  float acc[4] = {0.f, 0.f, 0.f, 0.f};
  for (int ii = 0; ii < 64; ii++) {
    int nl = wave * 64 + ii;
    float mv = memory[((size_t)b * NN + n0 + nl) * MM + lane];
#pragma unroll
    for (int r = 0; r < 4; r++) acc[r] += rwl[r][nl] * mv;
  }
#pragma unroll
  for (int r = 0; r < 4; r++) part[wave][r][lane] = acc[r];
  __syncthreads();
  { int r = t >> 6, m = t & 63;
    float s = part[0][r][m] + part[1][r][m] + part[2][r][m] + part[3][r][m];
    ws[WS_RPART + ((size_t)(b * 8 + chunk)) * 256 + t] = s; }
}

// ---- K7: reduce read partials + read projection + final output
__global__ void k_final(const float* __restrict__ W_read, const float* __restrict__ b_read,
                        const float* __restrict__ ws, float* __restrict__ out) {
  int b = blockIdx.x, t = threadIdx.x, lane = t & 63, wave = t >> 6;
  __shared__ float rds[256];
  float s = 0.f;
  for (int c = 0; c < 8; c++) s += ws[WS_RPART + ((size_t)(b * 8 + c)) * 256 + t];
  rds[t] = s;
  __syncthreads();
  for (int oi = 0; oi < 16; oi++) {
    int o = wave * 16 + oi;
    float acc = 0.f;
#pragma unroll
    for (int s2 = 0; s2 < 4; s2++) {
      int kk = s2 * 64 + lane;
      acc += W_read[o * 256 + kk] * rds[kk];
    }
#pragma unroll
    for (int off = 32; off >= 1; off >>= 1) acc += __shfl_xor(acc, off);
    if (lane == 0) {
      float ro = sigf(acc + b_read[o]);
      out[O_OUT + b * 64 + o] = sigf(ro + ws[WS_TASK + b * 64 + o]);
    }
  }
}

extern "C" void kernel_launch(void* const* d_in, const int* in_sizes, int n_in,
                              void* d_out, int out_size, void* d_ws, size_t ws_size,
                              hipStream_t stream) {
  (void)in_sizes; (void)n_in; (void)out_size; (void)ws_size;
  const float* task   = (const float*)d_in[0];
  const float* memory = (const float*)d_in[1];
  const float* links  = (const float*)d_in[2];
  const float* preads = (const float*)d_in[3];
  const float* prw    = (const float*)d_in[4];
  const float* pusage = (const float*)d_in[5];
  const float* pww    = (const float*)d_in[6];
  const float* prec   = (const float*)d_in[7];
  const float* h_prev = (const float*)d_in[8];
  const float* c_prev = (const float*)d_in[9];
  const float* W_ih   = (const float*)d_in[10];
  const float* W_hh   = (const float*)d_in[11];
  const float* b_lstm = (const float*)d_in[12];
  const float* W_out  = (const float*)d_in[13];
  const float* b_out  = (const float*)d_in[14];
  const float* W_read = (const float*)d_in[15];
  const float* b_read = (const float*)d_in[16];
  float* out = (float*)d_out;
  float* ws  = (float*)d_ws;

  k_gates_lstm<<<512, 256, 0, stream>>>(task, preads, h_prev, c_prev, W_ih, W_hh, b_lstm, ws);
  k_outproj_parse<<<134, 256, 0, stream>>>(W_out, b_out, ws);
  k_content<<<80, 1024, 0, stream>>>(memory, ws);
  k_write_path<<<16, 1024, 0, stream>>>(prw, pusage, pww, prec, ws, out);
  k_link<<<dim3(CHUNKS, BB), 512, 0, stream>>>(links, prw, memory, ws, out);
  k_readrw<<<128, 256, 0, stream>>>(memory, ws, out);
  k_final<<<16, 256, 0, stream>>>(W_read, b_read, ws, out);
}